// Round 1
// baseline (1184.628 us; speedup 1.0000x reference)
//
#include <hip/hip_runtime.h>
#include <hip/hip_bf16.h>

typedef __hip_bfloat16 bf16;
typedef __attribute__((ext_vector_type(8))) short bf16x8;
typedef __attribute__((ext_vector_type(4))) float f32x4;

#define B_ 8
#define S_ 512
#define D_ 1024
#define H_ 16
#define NEGV -9.0e15f

__device__ __forceinline__ float bf2f(bf16 x) { return __bfloat162float(x); }
__device__ __forceinline__ float us2f(unsigned short u) {
  union { unsigned int i; float f; } c; c.i = ((unsigned int)u) << 16; return c.f;
}
__device__ __forceinline__ unsigned short f2us(float f) {
  bf16 h = __float2bfloat16(f);
  unsigned short u; __builtin_memcpy(&u, &h, 2); return u;
}
__device__ __forceinline__ float ldx(const void* p, size_t i, int isbf) {
  return isbf ? bf2f(((const bf16*)p)[i]) : ((const float*)p)[i];
}
struct F4 { float x, y, z, w; };
__device__ __forceinline__ F4 ld4(const void* p, size_t i, int isbf) {
  F4 r;
  if (isbf) {
    ushort4 u = *(const ushort4*)((const bf16*)p + i);
    r.x = us2f(u.x); r.y = us2f(u.y); r.z = us2f(u.z); r.w = us2f(u.w);
  } else {
    float4 d = *(const float4*)((const float*)p + i);
    r.x = d.x; r.y = d.y; r.z = d.z; r.w = d.w;
  }
  return r;
}
// 8 consecutive elements as bf16x8; converts if source is f32
__device__ __forceinline__ bf16x8 ld8bf(const void* p, size_t i, int isbf) {
  if (isbf) return *(const bf16x8*)((const bf16*)p + i);
  float4 a = *(const float4*)((const float*)p + i);
  float4 b = *(const float4*)((const float*)p + i + 4);
  bf16x8 r;
  r[0] = (short)f2us(a.x); r[1] = (short)f2us(a.y);
  r[2] = (short)f2us(a.z); r[3] = (short)f2us(a.w);
  r[4] = (short)f2us(b.x); r[5] = (short)f2us(b.y);
  r[6] = (short)f2us(b.z); r[7] = (short)f2us(b.w);
  return r;
}
__device__ __forceinline__ f32x4 mfma_bf16(bf16x8 a, bf16x8 b, f32x4 c) {
  return __builtin_amdgcn_mfma_f32_16x16x32_bf16(a, b, c, 0, 0, 0);
}

// Dtype detector (round-3 verified: picks f32 on this harness).
__global__ void detect_k(const void* __restrict__ w, int* __restrict__ flag)
{
  if (threadIdx.x == 0 && blockIdx.x == 0) {
    const unsigned short* u = (const unsigned short*)w;
    int sane = 0;
    for (int i = 0; i < 1024; i += 2) {
      float a = fabsf(us2f(u[i]));
      if (a == 0.f || (a > 9.5e-7f && a < 8.f)) sane++;
    }
    *flag = (sane > 256) ? 1 : 0;
  }
}

// ---------------------------------------------------------------------------
// Weight transpose+convert: out[n][k] (bf16, 1024x1024) <- W[k][n] (per flag).
// ---------------------------------------------------------------------------
__global__ __launch_bounds__(256)
void wtrans_k(const void* __restrict__ W, size_t woff, bf16* __restrict__ out,
              const int* __restrict__ dflag)
{
  const int isbf = *dflag;
  __shared__ float t[64][68];
  const int tid = threadIdx.x;
  const int nt = blockIdx.x & 15, kt = blockIdx.x >> 4;
  {
    int r = tid >> 4, c4 = (tid & 15) * 4;
    #pragma unroll
    for (int i = 0; i < 4; i++) {
      int rr = r + i * 16;
      F4 v = ld4(W, woff + (size_t)(kt * 64 + rr) * 1024 + nt * 64 + c4, isbf);
      *(float4*)&t[rr][c4] = make_float4(v.x, v.y, v.z, v.w);
    }
  }
  __syncthreads();
  {
    int n = tid >> 4, k4 = (tid & 15) * 4;
    #pragma unroll
    for (int i = 0; i < 4; i++) {
      int nn = n + i * 16;
      ushort4 u;
      u.x = f2us(t[k4 + 0][nn]); u.y = f2us(t[k4 + 1][nn]);
      u.z = f2us(t[k4 + 2][nn]); u.w = f2us(t[k4 + 3][nn]);
      *(ushort4*)(out + (size_t)(nt * 64 + nn) * 1024 + kt * 64 + k4) = u;
    }
  }
}

// ---------------------------------------------------------------------------
// MFMA GEMM v2: C(Mx1024) = A @ Wt^T. A bf16 (ws) or external-dtype (AEXT).
// Tile 128x128, BK=64. Unpadded XOR-swizzled LDS (16B group g^(r&7)):
// conflict-free ds_read_b128 + 4x ds_write_b128/thread/k-step staging.
// MODE 0: QKV -> bf16 out: vtrans? [bh][d][s] : [bh][s][d]; (acc+bias)*scale
// MODE 1: gated(bf16)[r*1024+c] = sigmoid(acc+bias) * X_bf16[r*1024+c]
// MODE 2: outF f32 [r*1024+c] (accum? += : =) acc
// ---------------------------------------------------------------------------
template<int MODE, bool AEXT>
__global__ __launch_bounds__(256)
void gemm_mfma(const void* __restrict__ A, const bf16* __restrict__ Wt,
               const void* __restrict__ bias, bf16* __restrict__ outB,
               float* __restrict__ outF, const bf16* __restrict__ X,
               const int* __restrict__ dflag, size_t boff,
               float scale, int accum, int vtrans)
{
  const int isbf = *dflag;
  __shared__ short As[128 * 64];
  __shared__ short Bs[128 * 64];
  const int tid = threadIdx.x;
  const int w = tid >> 6, ln = tid & 63;
  const int ln15 = ln & 15, quad = ln >> 4;
  const int wm = (w & 1) * 64, wn = (w >> 1) * 64;
  const int bm = blockIdx.x * 128, bn = blockIdx.y * 128;
  const int r0 = tid >> 3, g0 = tid & 7;
  f32x4 acc[4][4];
  #pragma unroll
  for (int mt = 0; mt < 4; mt++)
    #pragma unroll
    for (int nt = 0; nt < 4; nt++) acc[mt][nt] = (f32x4)(0.0f);

  for (int k0 = 0; k0 < 1024; k0 += 64) {
    #pragma unroll
    for (int i = 0; i < 4; i++) {
      int r = r0 + i * 32;
      int gsw = ((g0 ^ (r & 7)) * 8);
      bf16x8 av = ld8bf(A, (size_t)(bm + r) * 1024 + k0 + g0 * 8, AEXT ? isbf : 1);
      *(bf16x8*)&As[r * 64 + gsw] = av;
      bf16x8 bv = *(const bf16x8*)(Wt + (size_t)(bn + r) * 1024 + k0 + g0 * 8);
      *(bf16x8*)&Bs[r * 64 + gsw] = bv;
    }
    __syncthreads();
    #pragma unroll
    for (int s = 0; s < 2; s++) {
      bf16x8 af[4], bfr[4];
      #pragma unroll
      for (int t = 0; t < 4; t++) {
        int ra = wm + t * 16 + ln15;
        af[t] = *(bf16x8*)&As[ra * 64 + (((s * 4 + quad) ^ (ra & 7)) * 8)];
        int rb = wn + t * 16 + ln15;
        bfr[t] = *(bf16x8*)&Bs[rb * 64 + (((s * 4 + quad) ^ (rb & 7)) * 8)];
      }
      #pragma unroll
      for (int mt = 0; mt < 4; mt++)
        #pragma unroll
        for (int nt = 0; nt < 4; nt++)
          acc[mt][nt] = mfma_bf16(af[mt], bfr[nt], acc[mt][nt]);
    }
    __syncthreads();
  }

  #pragma unroll
  for (int nt = 0; nt < 4; nt++) {
    int col = bn + wn + nt * 16 + ln15;
    float bv = 0.f;
    if constexpr (MODE != 2) bv = ldx(bias, boff + col, isbf);
    #pragma unroll
    for (int mt = 0; mt < 4; mt++) {
      #pragma unroll
      for (int r = 0; r < 4; r++) {
        int row = bm + wm + mt * 16 + quad * 4 + r;
        float v = acc[mt][nt][r];
        if constexpr (MODE == 0) {
          v = (v + bv) * scale;
          int bb = row >> 9, s = row & 511;
          int h = col >> 6, d0 = col & 63;
          size_t o = vtrans ? (((size_t)(bb * 16 + h) * 64 + d0) * 512 + s)
                            : (((size_t)(bb * 16 + h) * 512 + s) * 64 + d0);
          outB[o] = __float2bfloat16(v);
        } else if constexpr (MODE == 1) {
          v = v + bv;
          float x = bf2f(X[(size_t)row * 1024 + col]);
          outB[(size_t)row * 1024 + col] = __float2bfloat16(x / (1.f + __expf(-v)));
        } else {
          float* op = outF + (size_t)row * 1024 + col;
          float o = v;
          if (accum) o += *op;
          *op = o;
        }
      }
    }
  }
}

// ---------------------------------------------------------------------------
// G[row][r] = q_row . rel_emb[r] (bf16 q). One wave per row.
// ---------------------------------------------------------------------------
__global__ __launch_bounds__(256)
void qrel_k(const bf16* __restrict__ qbf, const void* __restrict__ rel_emb,
            float* __restrict__ G, const int* __restrict__ dflag)
{
  const int isbf = *dflag;
  __shared__ float rel[33][65];
  __shared__ float qw[4][64];
  const int tid = threadIdx.x;
  for (int i = tid; i < 33 * 64; i += 256)
    rel[i >> 6][i & 63] = ldx(rel_emb, i, isbf);
  const int wv = tid >> 6, lane = tid & 63;
  const size_t row = (size_t)blockIdx.x * 4 + wv;
  qw[wv][lane] = bf2f(qbf[row * 64 + lane]);
  __syncthreads();
  if (lane < 33) {
    float s = 0.f;
    #pragma unroll
    for (int d = 0; d < 64; d++) s += qw[wv][d] * rel[lane][d];
    G[row * 33 + lane] = s;
  }
}

// ---------------------------------------------------------------------------
// Fused MFMA QK^T + rel bias + softmax + bf16 attn + arel + top_attn.
// (round-5 verified, unchanged)
// ---------------------------------------------------------------------------
__global__ __launch_bounds__(256)
void score_k(const bf16* __restrict__ qbf, const bf16* __restrict__ kbf,
             const float* __restrict__ G, bf16* __restrict__ attn,
             float* __restrict__ arel, void* __restrict__ dout,
             int b_base, const int* __restrict__ dflag)
{
  __shared__ short smem[64 * 512];
  short* qs = smem;
  short* ks = smem + 64 * 72;
  float* gl = (float*)(smem + 2 * 64 * 72);
  const int tid = threadIdx.x;
  const int w = tid >> 6, ln = tid & 63;
  const int ln15 = ln & 15, quad = ln >> 4;
  const int bh = blockIdx.x, qt = blockIdx.y;
  const size_t qrow0 = (size_t)bh * 512 + qt * 64;

  #pragma unroll
  for (int i = 0; i < 4; i++) {
    int idx = tid + i * 256;
    int r = idx >> 4, c4 = (idx & 15) * 4;
    ushort4 u = *(const ushort4*)(qbf + (qrow0 + r) * 64 + c4);
    *(ushort4*)&qs[r * 72 + c4] = u;
  }
  for (int i = tid; i < 64 * 33; i += 256) {
    int r = i / 33, c = i - r * 33;
    gl[i] = G[(qrow0 + r) * 33 + c];
  }

  f32x4 acc[32];
  #pragma unroll
  for (int t = 0; t < 32; t++) acc[t] = (f32x4)(0.0f);

  const size_t kbase = (size_t)bh * 512 * 64;
  for (int kc = 0; kc < 8; kc++) {
    __syncthreads();
    #pragma unroll
    for (int i = 0; i < 4; i++) {
      int idx = tid + i * 256;
      int r = idx >> 4, c4 = (idx & 15) * 4;
      ushort4 u = *(const ushort4*)(kbf + kbase + (size_t)(kc * 64 + r) * 64 + c4);
      *(ushort4*)&ks[r * 72 + c4] = u;
    }
    __syncthreads();
    #pragma unroll
    for (int ds = 0; ds < 64; ds += 32) {
      bf16x8 a = *(bf16x8*)&qs[(w * 16 + ln15) * 72 + ds + quad * 8];
      #pragma unroll
      for (int nt = 0; nt < 4; nt++) {
        bf16x8 b = *(bf16x8*)&ks[(nt * 16 + ln15) * 72 + ds + quad * 8];
        acc[kc * 4 + nt] = mfma_bf16(a, b, acc[kc * 4 + nt]);
      }
    }
  }

  const int qg = qt * 64 + w * 16 + quad * 4;
  const int rowl0 = w * 16 + quad * 4;
  float mx[4], ssum[4], sle[4], sge[4];
  #pragma unroll
  for (int r = 0; r < 4; r++) mx[r] = -3.0e38f;
  for (int t = 0; t < 32; t++) {
    int k = t * 16 + ln15;
    #pragma unroll
    for (int r = 0; r < 4; r++) {
      int delta = k - (qg + r);
      int bkt = delta < -16 ? 0 : (delta > 16 ? 32 : delta + 16);
      float s = acc[t][r] + gl[(rowl0 + r) * 33 + bkt];
      acc[t][r] = s;
      mx[r] = fmaxf(mx[r], s);
    }
  }
  #pragma unroll
  for (int r = 0; r < 4; r++) {
    float m = mx[r];
    #pragma unroll
    for (int off = 1; off < 16; off <<= 1) m = fmaxf(m, __shfl_xor(m, off));
    mx[r] = m;
    ssum[r] = 0.f; sle[r] = 0.f; sge[r] = 0.f;
  }
  for (int t = 0; t < 32; t++) {
    int k = t * 16 + ln15;
    #pragma unroll
    for (int r = 0; r < 4; r++) {
      float p = __expf(acc[t][r] - mx[r]);
      acc[t][r] = p;
      ssum[r] += p;
      int delta = k - (qg + r);
      if (delta <= -16) sle[r] += p;
      if (delta >= 16) sge[r] += p;
    }
  }
  #pragma unroll
  for (int r = 0; r < 4; r++) {
    #pragma unroll
    for (int off = 1; off < 16; off <<= 1) {
      ssum[r] += __shfl_xor(ssum[r], off);
      sle[r] += __shfl_xor(sle[r], off);
      sge[r] += __shfl_xor(sge[r], off);
    }
  }
  float inv[4];
  #pragma unroll
  for (int r = 0; r < 4; r++) inv[r] = 1.f / ssum[r];
  if (ln15 == 0) {
    #pragma unroll
    for (int r = 0; r < 4; r++) {
      float* ap = arel + ((size_t)bh * 512 + qg + r) * 33;
      ap[0] = sle[r] * inv[r];
      ap[32] = sge[r] * inv[r];
    }
  }
  __syncthreads();

  for (int t = 0; t < 32; t++) {
    int ksw = (t * 16 + ln15) ^ (quad << 4);
    #pragma unroll
    for (int r = 0; r < 4; r++)
      smem[(rowl0 + r) * 512 + ksw] = (short)f2us(acc[t][r] * inv[r]);
  }
  __syncthreads();

  const int isbf = *dflag;
  const int toph = ((bh & 15) == 0);
  const int bg = b_base + (bh >> 4);
  for (int i = tid; i < 64 * 128; i += 256) {
    int r = i >> 7, c4 = (i & 127) * 4;
    int ksw = c4 ^ (((r >> 2) & 3) << 4);
    ushort4 u = *(ushort4*)&smem[r * 512 + ksw];
    *(ushort4*)(attn + ((size_t)bh * 512 + qt * 64 + r) * 512 + c4) = u;
    if (toph) {
      size_t o = (size_t)4194304 + (size_t)bg * 262144 + (size_t)(qt * 64 + r) * 512 + c4;
      if (isbf) {
        *(ushort4*)((bf16*)dout + o) = u;
      } else {
        float4 f = make_float4(us2f(u.x), us2f(u.y), us2f(u.z), us2f(u.w));
        *(float4*)((float*)dout + o) = f;
      }
    }
  }
  for (int i = tid; i < 64 * 33; i += 256) {
    int r = i / 33, bkt = i - r * 33;
    if (bkt == 0 || bkt == 32) continue;
    int qgr = qt * 64 + r;
    int k = qgr + bkt - 16;
    float v = 0.f;
    if (k >= 0 && k < 512) {
      int ksw = k ^ (((r >> 2) & 3) << 4);
      v = us2f((unsigned short)smem[r * 512 + ksw]);
    }
    arel[((size_t)bh * 512 + qgr) * 33 + bkt] = v;
  }
}

// ---------------------------------------------------------------------------
// MFMA ctx v2: C = attn(bf16) @ V (vt bf16 [bh][d][s]). Swizzled LDS,
// 16B staging. Writes ctx as bf16 [row][1024]. UREL adds arel@rel epilogue.
// ---------------------------------------------------------------------------
template<int UREL>
__global__ __launch_bounds__(256)
void ctx_mfma(const bf16* __restrict__ attn, const bf16* __restrict__ vt,
              const float* __restrict__ arel, const void* __restrict__ rel_emb,
              bf16* __restrict__ ctx, const int* __restrict__ dflag)
{
  __shared__ short smem[12800];       // 25.6 KB
  short* As = smem;                   // 128*64
  short* Vs = smem + 8192;            // 64*64
  const int tid = threadIdx.x;
  const int w = tid >> 6, ln = tid & 63;
  const int ln15 = ln & 15, quad = ln >> 4;
  const int bh = blockIdx.x, mt4 = blockIdx.y;
  const size_t abase = ((size_t)bh * 512 + mt4 * 128) * 512;
  const size_t vbase = (size_t)bh * 64 * 512;
  const int r0 = tid >> 3, g0 = tid & 7;
  f32x4 acc[2][4];
  #pragma unroll
  for (int mt = 0; mt < 2; mt++)
    #pragma unroll
    for (int nt = 0; nt < 4; nt++) acc[mt][nt] = (f32x4)(0.0f);

  for (int k0 = 0; k0 < 512; k0 += 64) {
    #pragma unroll
    for (int i = 0; i < 4; i++) {
      int r = r0 + i * 32;
      bf16x8 u = *(const bf16x8*)(attn + abase + (size_t)r * 512 + k0 + g0 * 8);
      *(bf16x8*)&As[r * 64 + ((g0 ^ (r & 7)) * 8)] = u;
    }
    #pragma unroll
    for (int i = 0; i < 2; i++) {
      int gi = tid + i * 256;
      int d = gi >> 3, g = gi & 7;
      bf16x8 u = *(const bf16x8*)(vt + vbase + (size_t)d * 512 + k0 + g * 8);
      *(bf16x8*)&Vs[d * 64 + ((g ^ (d & 7)) * 8)] = u;
    }
    __syncthreads();
    #pragma unroll
    for (int s = 0; s < 2; s++) {
      int ra0 = w * 32 + ln15, ra1 = w * 32 + 16 + ln15;
      bf16x8 a0 = *(bf16x8*)&As[ra0 * 64 + (((s * 4 + quad) ^ (ra0 & 7)) * 8)];
      bf16x8 a1 = *(bf16x8*)&As[ra1 * 64 + (((s * 4 + quad) ^ (ra1 & 7)) * 8)];
      #pragma unroll
      for (int nt = 0; nt < 4; nt++) {
        int rb = nt * 16 + ln15;
        bf16x8 b = *(bf16x8*)&Vs[rb * 64 + (((s * 4 + quad) ^ (rb & 7)) * 8)];
        acc[0][nt] = mfma_bf16(a0, b, acc[0][nt]);
        acc[1][nt] = mfma_bf16(a1, b, acc[1][nt]);
      }
    }
    __syncthreads();
  }

  if constexpr (UREL) {
    float* al = (float*)smem;             // 128*33 f32 = 16896 B
    float* rl = (float*)(smem + 8448);    // 33*64 f32 = 8448 B (ends 25344<=25600)
    const int isbf = *dflag;
    const float* ab = arel + ((size_t)bh * 512 + mt4 * 128) * 33;
    for (int i = tid; i < 4224; i += 256) al[i] = ab[i];
    for (int i = tid; i < 2112; i += 256) rl[i] = ldx(rel_emb, i, isbf);
    __syncthreads();
    #pragma unroll
    for (int mt = 0; mt < 2; mt++) {
      int rowl = w * 32 + mt * 16 + quad * 4;
      for (int rr = 0; rr < 33; rr++) {
        #pragma unroll
        for (int nt = 0; nt < 4; nt++) {
          float rv = rl[rr * 64 + nt * 16 + ln15];
          #pragma unroll
          for (int r = 0; r < 4; r++)
            acc[mt][nt][r] += al[(rowl + r) * 33 + rr] * rv;
        }
      }
    }
  }

  const int bl = bh >> 4, head = bh & 15;
  #pragma unroll
  for (int mt = 0; mt < 2; mt++) {
    #pragma unroll
    for (int r = 0; r < 4; r++) {
      int s = mt4 * 128 + w * 32 + mt * 16 + quad * 4 + r;
      #pragma unroll
      for (int nt = 0; nt < 4; nt++)
        ctx[((size_t)bl * 512 + s) * 1024 + head * 64 + nt * 16 + ln15] =
            __float2bfloat16(acc[mt][nt][r]);
    }
  }
}

// ---------------------------------------------------------------------------
// Edge h-projections from transposed V: block per bh, thread = 2 adjacent s.
// ---------------------------------------------------------------------------
__global__ __launch_bounds__(256)
void hv_k(const bf16* __restrict__ vt, const void* __restrict__ att_w,
          const void* __restrict__ att_b, int i0, int i1,
          float* __restrict__ h0, float* __restrict__ h1,
          const int* __restrict__ dflag)
{
  __shared__ float w0[64], w1[64];
  const int tid = threadIdx.x;
  const int bh = blockIdx.x;
  const int isbf = *dflag;
  if (tid < 64) {
    w0[tid] = ldx(att_w, i0 * 64 + tid, isbf);
    w1[tid] = ldx(att_w, i1 * 64 + tid, isbf);
  }
  __syncthreads();
  const bf16* vb = vt + (size_t)bh * 64 * 512 + tid * 2;
  float a00 = 0, a01 = 0, a10 = 0, a11 = 0;
  for (int d = 0; d < 64; d++) {
    ushort2 u = *(const ushort2*)(vb + (size_t)d * 512);
    float f0 = us2f(u.x), f1 = us2f(u.y);
    a00 += f0 * w0[d]; a10 += f1 * w0[d];
    a01 += f0 * w1[d]; a11 += f1 * w1[d];
  }
  float b0 = ldx(att_b, i0, isbf), b1 = ldx(att_b, i1, isbf);
  float* p0 = h0 + (size_t)bh * 512 + tid * 2;
  float* p1 = h1 + (size_t)bh * 512 + tid * 2;
  p0[0] = a00 + b0; p0[1] = a10 + b0;
  p1[0] = a01 + b1; p1[1] = a11 + b1;
}

// ---------------------------------------------------------------------------
// Fused edge view: masked softmax (rank-1 scores) + PV MFMA, no attn matrix
// round-trip through HBM. Block = (bh, 64 q-rows). Phase 1: each wave computes
// 16 rows' softmax (full-wave shfl reduce, math identical to old edge_attn_k),
// stores P bf16 into 64KB LDS with the verified XOR-16B-group swizzle.
// Phase 2: P @ V^T via mfma_16x16x32; V fragments loaded DIRECTLY from global
// (vt [bh][d][s]: a bf16x8 at vt[d*512+k] IS the B-fragment; 64KB/bh, L2-hot).
// Wave w: rows (w>>1)*32..+31, d cols (w&1)*32..+31 (b-frags reused 2x).
// ---------------------------------------------------------------------------
__global__ __launch_bounds__(256)
void edge_fused_k(const float* __restrict__ h0, const float* __restrict__ h1,
                  const int* __restrict__ grh, const bf16* __restrict__ vt,
                  bf16* __restrict__ ctx, int view)
{
  __shared__ short P[64 * 512];   // 64 KB, exactly like score_k
  const int tid = threadIdx.x;
  const int w = tid >> 6, ln = tid & 63;
  const int ln15 = ln & 15, quad = ln >> 4;
  const int bh = blockIdx.x, qt = blockIdx.y;
  const int bl = bh >> 4;

  // ---- phase 1: rows w*16 .. w*16+15, one full wave per row ----
  const int kb = ln * 8;
  {
    const float* hjp = h1 + (size_t)bh * 512 + kb;
    float4 hA = *(const float4*)hjp;
    float4 hB = *(const float4*)(hjp + 4);
    float hjv[8] = {hA.x, hA.y, hA.z, hA.w, hB.x, hB.y, hB.z, hB.w};
    const float* h0b = h0 + (size_t)bh * 512 + qt * 64 + w * 16;
    const int* grow = grh + ((size_t)bl * 512 + qt * 64 + w * 16) * 512 + kb;

    int4 ga = *(const int4*)grow;
    int4 gb = *(const int4*)(grow + 4);
    for (int rr = 0; rr < 16; rr++) {
      // prefetch next row's mask while this row computes
      int4 gan, gbn;
      if (rr < 15) {
        const int* gn = grow + (size_t)(rr + 1) * 512;
        gan = *(const int4*)gn;
        gbn = *(const int4*)(gn + 4);
      }
      int r = w * 16 + rr;
      int qi = qt * 64 + r;
      float hi = h0b[rr];
      int g[8] = {ga.x, ga.y, ga.z, ga.w, gb.x, gb.y, gb.z, gb.w};
      float e[8];
      float m = -3.0e38f;
      #pragma unroll
      for (int j = 0; j < 8; j++) {
        float ej = hi + hjv[j];
        ej = ej >= 0.f ? ej : 0.01f * ej;
        int k = kb + j;
        bool adj;
        if (view == 0) adj = g[j] > 1;
        else if (view == 1) adj = g[j] == ((k == qi) ? 4 : 2);
        else if (view == 2) adj = g[j] == ((k == qi) ? 4 : 3);
        else adj = g[j] == 4;
        e[j] = adj ? ej : NEGV;
        m = fmaxf(m, e[j]);
      }
      #pragma unroll
      for (int off = 32; off; off >>= 1) m = fmaxf(m, __shfl_xor(m, off));
      float ssum = 0.f;
      #pragma unroll
      for (int j = 0; j < 8; j++) { e[j] = __expf(e[j] - m); ssum += e[j]; }
      #pragma unroll
      for (int off = 32; off; off >>= 1) ssum += __shfl_xor(ssum, off);
      float inv = 1.f / ssum;
      bf16x8 pv;
      #pragma unroll
      for (int j = 0; j < 8; j++) pv[j] = (short)f2us(e[j] * inv);
      // logical col-group ln (cols ln*8..+7), stored at group ln^(r&7)
      *(bf16x8*)&P[r * 512 + ((ln ^ (r & 7)) * 8)] = pv;
      ga = gan; gb = gbn;
    }
  }
  __syncthreads();

  // ---- phase 2: ctx[rows, d] = P @ V^T, V straight from global ----
  const bf16* vb = vt + (size_t)bh * 64 * 512;
  const int m0 = (w >> 1) * 32, d0 = (w & 1) * 32;
  f32x4 acc[2][2];
  #pragma unroll
  for (int mt = 0; mt < 2; mt++)
    #pragma unroll
    for (int nt = 0; nt < 2; nt++) acc[mt][nt] = (f32x4)(0.0f);

  const int ra0 = m0 + ln15, ra1 = m0 + 16 + ln15;
  #pragma unroll 4
  for (int k0 = 0; k0 < 512; k0 += 32) {
    int gsel = (k0 >> 3) + quad;   // 16B-group index, 0..63
    bf16x8 a0 = *(bf16x8*)&P[ra0 * 512 + ((gsel ^ (ra0 & 7)) * 8)];
    bf16x8 a1 = *(bf16x8*)&P[ra1 * 512 + ((gsel ^ (ra1 & 7)) * 8)];
    #pragma unroll
    for (int nt = 0; nt < 2; nt++) {
      bf16x8 b = *(const bf16x8*)(vb + (size_t)(d0 + nt * 16 + ln15) * 512 + k0 + quad * 8);
      acc[0][nt] = mfma_bf16(a0, b, acc[0][nt]);
      acc[1][nt] = mfma_bf16(a1, b, acc[1][nt]);
    }
  }

  const int head = bh & 15;
  #pragma unroll
  for (int mt = 0; mt < 2; mt++) {
    #pragma unroll
    for (int r = 0; r < 4; r++) {
      int s = qt * 64 + m0 + mt * 16 + quad * 4 + r;
      #pragma unroll
      for (int nt = 0; nt < 2; nt++)
        ctx[((size_t)bl * 512 + s) * 1024 + head * 64 + d0 + nt * 16 + ln15] =
            __float2bfloat16(acc[mt][nt][r]);
    }
  }
}

// ---------------------------------------------------------------------------
__global__ __launch_bounds__(256)
void finish_k(const float* __restrict__ acc, const void* __restrict__ sub_b,
              void* __restrict__ dout, const int* __restrict__ dflag)
{
  const int isbf = *dflag;
  int i = blockIdx.x * 256 + threadIdx.x;
  float4 a = ((const float4*)acc)[i];
  int c = (i * 4) & 1023;
  float o0 = a.x + ldx(sub_b, c + 0, isbf);
  float o1 = a.y + ldx(sub_b, c + 1, isbf);
  float o2 = a.z + ldx(sub_b, c + 2, isbf);
  float o3 = a.w + ldx(sub_b, c + 3, isbf);
  if (isbf) {
    ushort4 u;
    u.x = f2us(o0); u.y = f2us(o1); u.z = f2us(o2); u.w = f2us(o3);
    ((ushort4*)dout)[i] = u;
  } else {
    ((float4*)dout)[i] = make_float4(o0, o1, o2, o3);
  }
}

// ---------------------------------------------------------------------------
extern "C" void kernel_launch(void* const* d_in, const int* in_sizes, int n_in,
                              void* d_out, int out_size, void* d_ws, size_t ws_size,
                              hipStream_t stream)
{
  const void* key   = d_in[0];
  const void* value = d_in[1];
  const void* query = d_in[2];
  const int*  grh   = (const int*)d_in[3];
  const void* Wq = d_in[5];
  const void* bq = d_in[6];
  const void* Wk = d_in[7];
  const void* bk = d_in[8];
  const void* Wv = d_in[9];
  const void* bv = d_in[10];
  const void* rel_emb = d_in[11];
  const void* att_w = d_in[12];
  const void* att_b = d_in[13];
  const void* gate_w = d_in[14];
  const void* gate_b = d_in[15];
  const void* sub_w = d_in[16];
  const void* sub_b = d_in[17];

  // chunking: fixed 19,595,280 fl + NB * 2,891,776 fl
  size_t ws_f = ws_size / 4;
  int NB = 1;
  for (int cand = 8; cand >= 1; cand >>= 1) {
    size_t need = 19595280ull + (size_t)cand * 2891776ull;
    if (need <= ws_f) { NB = cand; break; }
  }
  const int nch = 8 / NB;

  int* dflag = (int*)d_ws;
  float* base = (float*)d_ws;
  bf16* qbf = (bf16*)(base + 16);
  bf16* kbf = (bf16*)(base + 16 + 2097152);
  bf16* vtb = (bf16*)(base + 16 + 2 * 2097152);
  bf16* Wt  = (bf16*)(base + 16 + 3 * 2097152);
  float* G  = base + 16 + 3 * 2097152 + 6815744;
  float* h0 = G + 2162688;
  float* h1 = h0 + 65536;
  float* out_acc = h1 + 65536;
  bf16* ctx_c   = (bf16*)(out_acc + 4194304);
  bf16* gated_c = ctx_c + (size_t)NB * 524288;
  float* arel_c = (float*)(gated_c + (size_t)NB * 524288);
  bf16*  attn_c = (bf16*)(arel_c + (size_t)NB * 270336);

  const size_t WSL = 1048576;   // bf16 elems per weight slot

  detect_k<<<dim3(1), dim3(64), 0, stream>>>(Wq, dflag);

  // weights -> bf16 [n][k]: slots 0..2 QKV, 3..7 gate {0,5,1,2,3}, 8..12 sub
  wtrans_k<<<dim3(256), dim3(256), 0, stream>>>(Wq, 0, Wt + 0 * WSL, dflag);
  wtrans_k<<<dim3(256), dim3(256), 0, stream>>>(Wk, 0, Wt + 1 * WSL, dflag);
  wtrans_k<<<dim3(256), dim3(256), 0, stream>>>(Wv, 0, Wt + 2 * WSL, dflag);
  const int gate_srcs[5] = {0, 5, 1, 2, 3};
  for (int j = 0; j < 5; j++)
    wtrans_k<<<dim3(256), dim3(256), 0, stream>>>(gate_w, (size_t)gate_srcs[j] * WSL,
                                                  Wt + (size_t)(3 + j) * WSL, dflag);
  for (int c = 0; c < 5; c++)
    wtrans_k<<<dim3(256), dim3(256), 0, stream>>>(sub_w, (size_t)c * WSL,
                                                  Wt + (size_t)(8 + c) * WSL, dflag);

  // QKV projections (q scaled; v transposed to [bh][d][s])
  gemm_mfma<0, true><<<dim3(32, 8), dim3(256), 0, stream>>>(
      query, Wt + 0 * WSL, bq, qbf, nullptr, nullptr, dflag, 0, 0.125f, 0, 0);
  gemm_mfma<0, true><<<dim3(32, 8), dim3(256), 0, stream>>>(
      key, Wt + 1 * WSL, bk, kbf, nullptr, nullptr, dflag, 0, 1.0f, 0, 0);
  gemm_mfma<0, true><<<dim3(32, 8), dim3(256), 0, stream>>>(
      value, Wt + 2 * WSL, bv, vtb, nullptr, nullptr, dflag, 0, 1.0f, 0, 1);

  qrel_k<<<dim3(16384), dim3(256), 0, stream>>>(qbf, rel_emb, G, dflag);

  // main view
  for (int c = 0; c < nch; c++) {
    size_t ro = (size_t)c * NB * 8192;
    score_k<<<dim3(NB * 16, 8), dim3(256), 0, stream>>>(
        qbf + ro * 64, kbf + ro * 64, G + ro * 33, attn_c, arel_c,
        d_out, c * NB, dflag);
    ctx_mfma<1><<<dim3(NB * 16, 4), dim3(256), 0, stream>>>(
        attn_c, vtb + ro * 64, arel_c, rel_emb, ctx_c, dflag);
    gemm_mfma<1, false><<<dim3(NB * 4, 8), dim3(256), 0, stream>>>(
        ctx_c, Wt + 3 * WSL, gate_b, gated_c, nullptr, ctx_c, dflag, 0, 1.f, 0, 0);
    gemm_mfma<2, false><<<dim3(NB * 4, 8), dim3(256), 0, stream>>>(
        gated_c, Wt + 8 * WSL, nullptr, nullptr, out_acc + ro * 64, nullptr,
        dflag, 0, 1.f, 0, 0);
  }

  // edge views: fused softmax+PV (no attn HBM round-trip)
  const int i0s[4] = {6, 0, 2, 4};
  const int i1s[4] = {7, 1, 3, 5};
  const int gis[4] = {5, 1, 2, 3};
  for (int v = 0; v < 4; v++) {
    hv_k<<<dim3(128), dim3(256), 0, stream>>>(vtb, att_w, att_b, i0s[v], i1s[v],
                                              h0, h1, dflag);
    for (int c = 0; c < nch; c++) {
      size_t ro = (size_t)c * NB * 8192;
      edge_fused_k<<<dim3(NB * 16, 8), dim3(256), 0, stream>>>(
          h0 + ro, h1 + ro, grh + (size_t)c * NB * 262144, vtb + ro * 64,
          ctx_c, v);
      gemm_mfma<1, false><<<dim3(NB * 4, 8), dim3(256), 0, stream>>>(
          ctx_c, Wt + (size_t)(4 + v) * WSL, gate_b, gated_c, nullptr, ctx_c,
          dflag, (size_t)gis[v] * 1024, 1.f, 0, 0);
      gemm_mfma<2, false><<<dim3(NB * 4, 8), dim3(256), 0, stream>>>(
          gated_c, Wt + (size_t)(9 + v) * WSL, nullptr, nullptr,
          out_acc + ro * 64, nullptr, dflag, 0, 1.f, 1, 0);
    }
  }

  finish_k<<<dim3(4096), dim3(256), 0, stream>>>(out_acc, sub_b, d_out, dflag);
}

// Round 2
// 1158.793 us; speedup vs baseline: 1.0223x; 1.0223x over previous
//
#include <hip/hip_runtime.h>
#include <hip/hip_bf16.h>

typedef __hip_bfloat16 bf16;
typedef __attribute__((ext_vector_type(8))) short bf16x8;
typedef __attribute__((ext_vector_type(4))) float f32x4;

#define B_ 8
#define S_ 512
#define D_ 1024
#define H_ 16
#define NEGV -9.0e15f

__device__ __forceinline__ float bf2f(bf16 x) { return __bfloat162float(x); }
__device__ __forceinline__ float us2f(unsigned short u) {
  union { unsigned int i; float f; } c; c.i = ((unsigned int)u) << 16; return c.f;
}
__device__ __forceinline__ unsigned short f2us(float f) {
  bf16 h = __float2bfloat16(f);
  unsigned short u; __builtin_memcpy(&u, &h, 2); return u;
}
__device__ __forceinline__ float ldx(const void* p, size_t i, int isbf) {
  return isbf ? bf2f(((const bf16*)p)[i]) : ((const float*)p)[i];
}
struct F4 { float x, y, z, w; };
__device__ __forceinline__ F4 ld4(const void* p, size_t i, int isbf) {
  F4 r;
  if (isbf) {
    ushort4 u = *(const ushort4*)((const bf16*)p + i);
    r.x = us2f(u.x); r.y = us2f(u.y); r.z = us2f(u.z); r.w = us2f(u.w);
  } else {
    float4 d = *(const float4*)((const float*)p + i);
    r.x = d.x; r.y = d.y; r.z = d.z; r.w = d.w;
  }
  return r;
}
// 8 consecutive elements as bf16x8; converts if source is f32
__device__ __forceinline__ bf16x8 ld8bf(const void* p, size_t i, int isbf) {
  if (isbf) return *(const bf16x8*)((const bf16*)p + i);
  float4 a = *(const float4*)((const float*)p + i);
  float4 b = *(const float4*)((const float*)p + i + 4);
  bf16x8 r;
  r[0] = (short)f2us(a.x); r[1] = (short)f2us(a.y);
  r[2] = (short)f2us(a.z); r[3] = (short)f2us(a.w);
  r[4] = (short)f2us(b.x); r[5] = (short)f2us(b.y);
  r[6] = (short)f2us(b.z); r[7] = (short)f2us(b.w);
  return r;
}
__device__ __forceinline__ f32x4 mfma_bf16(bf16x8 a, bf16x8 b, f32x4 c) {
  return __builtin_amdgcn_mfma_f32_16x16x32_bf16(a, b, c, 0, 0, 0);
}

// Dtype detector (round-3 verified: picks f32 on this harness).
__global__ void detect_k(const void* __restrict__ w, int* __restrict__ flag)
{
  if (threadIdx.x == 0 && blockIdx.x == 0) {
    const unsigned short* u = (const unsigned short*)w;
    int sane = 0;
    for (int i = 0; i < 1024; i += 2) {
      float a = fabsf(us2f(u[i]));
      if (a == 0.f || (a > 9.5e-7f && a < 8.f)) sane++;
    }
    *flag = (sane > 256) ? 1 : 0;
  }
}

// ---------------------------------------------------------------------------
// Weight transpose+convert: out[n][k] (bf16, 1024x1024) <- W[k][n] (per flag).
// ---------------------------------------------------------------------------
__global__ __launch_bounds__(256)
void wtrans_k(const void* __restrict__ W, size_t woff, bf16* __restrict__ out,
              const int* __restrict__ dflag)
{
  const int isbf = *dflag;
  __shared__ float t[64][68];
  const int tid = threadIdx.x;
  const int nt = blockIdx.x & 15, kt = blockIdx.x >> 4;
  {
    int r = tid >> 4, c4 = (tid & 15) * 4;
    #pragma unroll
    for (int i = 0; i < 4; i++) {
      int rr = r + i * 16;
      F4 v = ld4(W, woff + (size_t)(kt * 64 + rr) * 1024 + nt * 64 + c4, isbf);
      *(float4*)&t[rr][c4] = make_float4(v.x, v.y, v.z, v.w);
    }
  }
  __syncthreads();
  {
    int n = tid >> 4, k4 = (tid & 15) * 4;
    #pragma unroll
    for (int i = 0; i < 4; i++) {
      int nn = n + i * 16;
      ushort4 u;
      u.x = f2us(t[k4 + 0][nn]); u.y = f2us(t[k4 + 1][nn]);
      u.z = f2us(t[k4 + 2][nn]); u.w = f2us(t[k4 + 3][nn]);
      *(ushort4*)(out + (size_t)(nt * 64 + nn) * 1024 + kt * 64 + k4) = u;
    }
  }
}

// ---------------------------------------------------------------------------
// MFMA GEMM v2: C(Mx1024) = A @ Wt^T. A bf16 (ws) or external-dtype (AEXT).
// Tile 128x128, BK=64. Unpadded XOR-swizzled LDS (16B group g^(r&7)):
// conflict-free ds_read_b128 + 4x ds_write_b128/thread/k-step staging.
// MODE 0: QKV -> bf16 out: vtrans? [bh][d][s] : [bh][s][d]; (acc+bias)*scale
// MODE 1: gated(bf16)[r*1024+c] = sigmoid(acc+bias) * X_bf16[r*1024+c]
// MODE 2: outF f32 [r*1024+c] (accum? += : =) acc
// ---------------------------------------------------------------------------
template<int MODE, bool AEXT>
__global__ __launch_bounds__(256)
void gemm_mfma(const void* __restrict__ A, const bf16* __restrict__ Wt,
               const void* __restrict__ bias, bf16* __restrict__ outB,
               float* __restrict__ outF, const bf16* __restrict__ X,
               const int* __restrict__ dflag, size_t boff,
               float scale, int accum, int vtrans)
{
  const int isbf = *dflag;
  __shared__ short As[128 * 64];
  __shared__ short Bs[128 * 64];
  const int tid = threadIdx.x;
  const int w = tid >> 6, ln = tid & 63;
  const int ln15 = ln & 15, quad = ln >> 4;
  const int wm = (w & 1) * 64, wn = (w >> 1) * 64;
  const int bm = blockIdx.x * 128, bn = blockIdx.y * 128;
  const int r0 = tid >> 3, g0 = tid & 7;
  f32x4 acc[4][4];
  #pragma unroll
  for (int mt = 0; mt < 4; mt++)
    #pragma unroll
    for (int nt = 0; nt < 4; nt++) acc[mt][nt] = (f32x4)(0.0f);

  for (int k0 = 0; k0 < 1024; k0 += 64) {
    #pragma unroll
    for (int i = 0; i < 4; i++) {
      int r = r0 + i * 32;
      int gsw = ((g0 ^ (r & 7)) * 8);
      bf16x8 av = ld8bf(A, (size_t)(bm + r) * 1024 + k0 + g0 * 8, AEXT ? isbf : 1);
      *(bf16x8*)&As[r * 64 + gsw] = av;
      bf16x8 bv = *(const bf16x8*)(Wt + (size_t)(bn + r) * 1024 + k0 + g0 * 8);
      *(bf16x8*)&Bs[r * 64 + gsw] = bv;
    }
    __syncthreads();
    #pragma unroll
    for (int s = 0; s < 2; s++) {
      bf16x8 af[4], bfr[4];
      #pragma unroll
      for (int t = 0; t < 4; t++) {
        int ra = wm + t * 16 + ln15;
        af[t] = *(bf16x8*)&As[ra * 64 + (((s * 4 + quad) ^ (ra & 7)) * 8)];
        int rb = wn + t * 16 + ln15;
        bfr[t] = *(bf16x8*)&Bs[rb * 64 + (((s * 4 + quad) ^ (rb & 7)) * 8)];
      }
      #pragma unroll
      for (int mt = 0; mt < 4; mt++)
        #pragma unroll
        for (int nt = 0; nt < 4; nt++)
          acc[mt][nt] = mfma_bf16(af[mt], bfr[nt], acc[mt][nt]);
    }
    __syncthreads();
  }

  #pragma unroll
  for (int nt = 0; nt < 4; nt++) {
    int col = bn + wn + nt * 16 + ln15;
    float bv = 0.f;
    if constexpr (MODE != 2) bv = ldx(bias, boff + col, isbf);
    #pragma unroll
    for (int mt = 0; mt < 4; mt++) {
      #pragma unroll
      for (int r = 0; r < 4; r++) {
        int row = bm + wm + mt * 16 + quad * 4 + r;
        float v = acc[mt][nt][r];
        if constexpr (MODE == 0) {
          v = (v + bv) * scale;
          int bb = row >> 9, s = row & 511;
          int h = col >> 6, d0 = col & 63;
          size_t o = vtrans ? (((size_t)(bb * 16 + h) * 64 + d0) * 512 + s)
                            : (((size_t)(bb * 16 + h) * 512 + s) * 64 + d0);
          outB[o] = __float2bfloat16(v);
        } else if constexpr (MODE == 1) {
          v = v + bv;
          float x = bf2f(X[(size_t)row * 1024 + col]);
          outB[(size_t)row * 1024 + col] = __float2bfloat16(x / (1.f + __expf(-v)));
        } else {
          float* op = outF + (size_t)row * 1024 + col;
          float o = v;
          if (accum) o += *op;
          *op = o;
        }
      }
    }
  }
}

// ---------------------------------------------------------------------------
// G[row][r] = q_row . rel_emb[r] (bf16 q). One wave per row.
// ---------------------------------------------------------------------------
__global__ __launch_bounds__(256)
void qrel_k(const bf16* __restrict__ qbf, const void* __restrict__ rel_emb,
            float* __restrict__ G, const int* __restrict__ dflag)
{
  const int isbf = *dflag;
  __shared__ float rel[33][65];
  __shared__ float qw[4][64];
  const int tid = threadIdx.x;
  for (int i = tid; i < 33 * 64; i += 256)
    rel[i >> 6][i & 63] = ldx(rel_emb, i, isbf);
  const int wv = tid >> 6, lane = tid & 63;
  const size_t row = (size_t)blockIdx.x * 4 + wv;
  qw[wv][lane] = bf2f(qbf[row * 64 + lane]);
  __syncthreads();
  if (lane < 33) {
    float s = 0.f;
    #pragma unroll
    for (int d = 0; d < 64; d++) s += qw[wv][d] * rel[lane][d];
    G[row * 33 + lane] = s;
  }
}

// ---------------------------------------------------------------------------
// Fused MFMA QK^T + rel bias + softmax + bf16 attn + arel + top_attn.
// (round-5 verified, unchanged)
// ---------------------------------------------------------------------------
__global__ __launch_bounds__(256)
void score_k(const bf16* __restrict__ qbf, const bf16* __restrict__ kbf,
             const float* __restrict__ G, bf16* __restrict__ attn,
             float* __restrict__ arel, void* __restrict__ dout,
             int b_base, const int* __restrict__ dflag)
{
  __shared__ short smem[64 * 512];
  short* qs = smem;
  short* ks = smem + 64 * 72;
  float* gl = (float*)(smem + 2 * 64 * 72);
  const int tid = threadIdx.x;
  const int w = tid >> 6, ln = tid & 63;
  const int ln15 = ln & 15, quad = ln >> 4;
  const int bh = blockIdx.x, qt = blockIdx.y;
  const size_t qrow0 = (size_t)bh * 512 + qt * 64;

  #pragma unroll
  for (int i = 0; i < 4; i++) {
    int idx = tid + i * 256;
    int r = idx >> 4, c4 = (idx & 15) * 4;
    ushort4 u = *(const ushort4*)(qbf + (qrow0 + r) * 64 + c4);
    *(ushort4*)&qs[r * 72 + c4] = u;
  }
  for (int i = tid; i < 64 * 33; i += 256) {
    int r = i / 33, c = i - r * 33;
    gl[i] = G[(qrow0 + r) * 33 + c];
  }

  f32x4 acc[32];
  #pragma unroll
  for (int t = 0; t < 32; t++) acc[t] = (f32x4)(0.0f);

  const size_t kbase = (size_t)bh * 512 * 64;
  for (int kc = 0; kc < 8; kc++) {
    __syncthreads();
    #pragma unroll
    for (int i = 0; i < 4; i++) {
      int idx = tid + i * 256;
      int r = idx >> 4, c4 = (idx & 15) * 4;
      ushort4 u = *(const ushort4*)(kbf + kbase + (size_t)(kc * 64 + r) * 64 + c4);
      *(ushort4*)&ks[r * 72 + c4] = u;
    }
    __syncthreads();
    #pragma unroll
    for (int ds = 0; ds < 64; ds += 32) {
      bf16x8 a = *(bf16x8*)&qs[(w * 16 + ln15) * 72 + ds + quad * 8];
      #pragma unroll
      for (int nt = 0; nt < 4; nt++) {
        bf16x8 b = *(bf16x8*)&ks[(nt * 16 + ln15) * 72 + ds + quad * 8];
        acc[kc * 4 + nt] = mfma_bf16(a, b, acc[kc * 4 + nt]);
      }
    }
  }

  const int qg = qt * 64 + w * 16 + quad * 4;
  const int rowl0 = w * 16 + quad * 4;
  float mx[4], ssum[4], sle[4], sge[4];
  #pragma unroll
  for (int r = 0; r < 4; r++) mx[r] = -3.0e38f;
  for (int t = 0; t < 32; t++) {
    int k = t * 16 + ln15;
    #pragma unroll
    for (int r = 0; r < 4; r++) {
      int delta = k - (qg + r);
      int bkt = delta < -16 ? 0 : (delta > 16 ? 32 : delta + 16);
      float s = acc[t][r] + gl[(rowl0 + r) * 33 + bkt];
      acc[t][r] = s;
      mx[r] = fmaxf(mx[r], s);
    }
  }
  #pragma unroll
  for (int r = 0; r < 4; r++) {
    float m = mx[r];
    #pragma unroll
    for (int off = 1; off < 16; off <<= 1) m = fmaxf(m, __shfl_xor(m, off));
    mx[r] = m;
    ssum[r] = 0.f; sle[r] = 0.f; sge[r] = 0.f;
  }
  for (int t = 0; t < 32; t++) {
    int k = t * 16 + ln15;
    #pragma unroll
    for (int r = 0; r < 4; r++) {
      float p = __expf(acc[t][r] - mx[r]);
      acc[t][r] = p;
      ssum[r] += p;
      int delta = k - (qg + r);
      if (delta <= -16) sle[r] += p;
      if (delta >= 16) sge[r] += p;
    }
  }
  #pragma unroll
  for (int r = 0; r < 4; r++) {
    #pragma unroll
    for (int off = 1; off < 16; off <<= 1) {
      ssum[r] += __shfl_xor(ssum[r], off);
      sle[r] += __shfl_xor(sle[r], off);
      sge[r] += __shfl_xor(sge[r], off);
    }
  }
  float inv[4];
  #pragma unroll
  for (int r = 0; r < 4; r++) inv[r] = 1.f / ssum[r];
  if (ln15 == 0) {
    #pragma unroll
    for (int r = 0; r < 4; r++) {
      float* ap = arel + ((size_t)bh * 512 + qg + r) * 33;
      ap[0] = sle[r] * inv[r];
      ap[32] = sge[r] * inv[r];
    }
  }
  __syncthreads();

  for (int t = 0; t < 32; t++) {
    int ksw = (t * 16 + ln15) ^ (quad << 4);
    #pragma unroll
    for (int r = 0; r < 4; r++)
      smem[(rowl0 + r) * 512 + ksw] = (short)f2us(acc[t][r] * inv[r]);
  }
  __syncthreads();

  const int isbf = *dflag;
  const int toph = ((bh & 15) == 0);
  const int bg = b_base + (bh >> 4);
  for (int i = tid; i < 64 * 128; i += 256) {
    int r = i >> 7, c4 = (i & 127) * 4;
    int ksw = c4 ^ (((r >> 2) & 3) << 4);
    ushort4 u = *(ushort4*)&smem[r * 512 + ksw];
    *(ushort4*)(attn + ((size_t)bh * 512 + qt * 64 + r) * 512 + c4) = u;
    if (toph) {
      size_t o = (size_t)4194304 + (size_t)bg * 262144 + (size_t)(qt * 64 + r) * 512 + c4;
      if (isbf) {
        *(ushort4*)((bf16*)dout + o) = u;
      } else {
        float4 f = make_float4(us2f(u.x), us2f(u.y), us2f(u.z), us2f(u.w));
        *(float4*)((float*)dout + o) = f;
      }
    }
  }
  for (int i = tid; i < 64 * 33; i += 256) {
    int r = i / 33, bkt = i - r * 33;
    if (bkt == 0 || bkt == 32) continue;
    int qgr = qt * 64 + r;
    int k = qgr + bkt - 16;
    float v = 0.f;
    if (k >= 0 && k < 512) {
      int ksw = k ^ (((r >> 2) & 3) << 4);
      v = us2f((unsigned short)smem[r * 512 + ksw]);
    }
    arel[((size_t)bh * 512 + qgr) * 33 + bkt] = v;
  }
}

// ---------------------------------------------------------------------------
// MFMA ctx v2: C = attn(bf16) @ V (vt bf16 [bh][d][s]). Swizzled LDS,
// 16B staging. Writes ctx as bf16 [row][1024]. UREL adds arel@rel epilogue.
// ---------------------------------------------------------------------------
template<int UREL>
__global__ __launch_bounds__(256)
void ctx_mfma(const bf16* __restrict__ attn, const bf16* __restrict__ vt,
              const float* __restrict__ arel, const void* __restrict__ rel_emb,
              bf16* __restrict__ ctx, const int* __restrict__ dflag)
{
  __shared__ short smem[12800];       // 25.6 KB
  short* As = smem;                   // 128*64
  short* Vs = smem + 8192;            // 64*64
  const int tid = threadIdx.x;
  const int w = tid >> 6, ln = tid & 63;
  const int ln15 = ln & 15, quad = ln >> 4;
  const int bh = blockIdx.x, mt4 = blockIdx.y;
  const size_t abase = ((size_t)bh * 512 + mt4 * 128) * 512;
  const size_t vbase = (size_t)bh * 64 * 512;
  const int r0 = tid >> 3, g0 = tid & 7;
  f32x4 acc[2][4];
  #pragma unroll
  for (int mt = 0; mt < 2; mt++)
    #pragma unroll
    for (int nt = 0; nt < 4; nt++) acc[mt][nt] = (f32x4)(0.0f);

  for (int k0 = 0; k0 < 512; k0 += 64) {
    #pragma unroll
    for (int i = 0; i < 4; i++) {
      int r = r0 + i * 32;
      bf16x8 u = *(const bf16x8*)(attn + abase + (size_t)r * 512 + k0 + g0 * 8);
      *(bf16x8*)&As[r * 64 + ((g0 ^ (r & 7)) * 8)] = u;
    }
    #pragma unroll
    for (int i = 0; i < 2; i++) {
      int gi = tid + i * 256;
      int d = gi >> 3, g = gi & 7;
      bf16x8 u = *(const bf16x8*)(vt + vbase + (size_t)d * 512 + k0 + g * 8);
      *(bf16x8*)&Vs[d * 64 + ((g ^ (d & 7)) * 8)] = u;
    }
    __syncthreads();
    #pragma unroll
    for (int s = 0; s < 2; s++) {
      int ra0 = w * 32 + ln15, ra1 = w * 32 + 16 + ln15;
      bf16x8 a0 = *(bf16x8*)&As[ra0 * 64 + (((s * 4 + quad) ^ (ra0 & 7)) * 8)];
      bf16x8 a1 = *(bf16x8*)&As[ra1 * 64 + (((s * 4 + quad) ^ (ra1 & 7)) * 8)];
      #pragma unroll
      for (int nt = 0; nt < 4; nt++) {
        int rb = nt * 16 + ln15;
        bf16x8 b = *(bf16x8*)&Vs[rb * 64 + (((s * 4 + quad) ^ (rb & 7)) * 8)];
        acc[0][nt] = mfma_bf16(a0, b, acc[0][nt]);
        acc[1][nt] = mfma_bf16(a1, b, acc[1][nt]);
      }
    }
    __syncthreads();
  }

  if constexpr (UREL) {
    float* al = (float*)smem;             // 128*33 f32 = 16896 B
    float* rl = (float*)(smem + 8448);    // 33*64 f32 = 8448 B (ends 25344<=25600)
    const int isbf = *dflag;
    const float* ab = arel + ((size_t)bh * 512 + mt4 * 128) * 33;
    for (int i = tid; i < 4224; i += 256) al[i] = ab[i];
    for (int i = tid; i < 2112; i += 256) rl[i] = ldx(rel_emb, i, isbf);
    __syncthreads();
    #pragma unroll
    for (int mt = 0; mt < 2; mt++) {
      int rowl = w * 32 + mt * 16 + quad * 4;
      for (int rr = 0; rr < 33; rr++) {
        #pragma unroll
        for (int nt = 0; nt < 4; nt++) {
          float rv = rl[rr * 64 + nt * 16 + ln15];
          #pragma unroll
          for (int r = 0; r < 4; r++)
            acc[mt][nt][r] += al[(rowl + r) * 33 + rr] * rv;
        }
      }
    }
  }

  const int bl = bh >> 4, head = bh & 15;
  #pragma unroll
  for (int mt = 0; mt < 2; mt++) {
    #pragma unroll
    for (int r = 0; r < 4; r++) {
      int s = mt4 * 128 + w * 32 + mt * 16 + quad * 4 + r;
      #pragma unroll
      for (int nt = 0; nt < 4; nt++)
        ctx[((size_t)bl * 512 + s) * 1024 + head * 64 + nt * 16 + ln15] =
            __float2bfloat16(acc[mt][nt][r]);
    }
  }
}

// ---------------------------------------------------------------------------
// Edge h-projections from transposed V: block per bh, thread = 2 adjacent s.
// ---------------------------------------------------------------------------
__global__ __launch_bounds__(256)
void hv_k(const bf16* __restrict__ vt, const void* __restrict__ att_w,
          const void* __restrict__ att_b, int i0, int i1,
          float* __restrict__ h0, float* __restrict__ h1,
          const int* __restrict__ dflag)
{
  __shared__ float w0[64], w1[64];
  const int tid = threadIdx.x;
  const int bh = blockIdx.x;
  const int isbf = *dflag;
  if (tid < 64) {
    w0[tid] = ldx(att_w, i0 * 64 + tid, isbf);
    w1[tid] = ldx(att_w, i1 * 64 + tid, isbf);
  }
  __syncthreads();
  const bf16* vb = vt + (size_t)bh * 64 * 512 + tid * 2;
  float a00 = 0, a01 = 0, a10 = 0, a11 = 0;
  for (int d = 0; d < 64; d++) {
    ushort2 u = *(const ushort2*)(vb + (size_t)d * 512);
    float f0 = us2f(u.x), f1 = us2f(u.y);
    a00 += f0 * w0[d]; a10 += f1 * w0[d];
    a01 += f0 * w1[d]; a11 += f1 * w1[d];
  }
  float b0 = ldx(att_b, i0, isbf), b1 = ldx(att_b, i1, isbf);
  float* p0 = h0 + (size_t)bh * 512 + tid * 2;
  float* p1 = h1 + (size_t)bh * 512 + tid * 2;
  p0[0] = a00 + b0; p0[1] = a10 + b0;
  p1[0] = a01 + b1; p1[1] = a11 + b1;
}

// ---------------------------------------------------------------------------
// Fused edge view v2: masked softmax (rank-1 scores) + PV MFMA, no attn HBM
// round-trip. 32 q-rows per block (P = 32x512 bf16 = 32 KB LDS -> 5 blocks/CU,
// ~20 waves/CU vs v1's 8). Phase 1: each wave owns 8 rows, unroll-2 so two
// independent softmax DAGs interleave (hide shfl/exp latency). Phase 2:
// wave w: rows (w>>1)*16, d cols (w&1)*32; V fragments straight from global
// (vt [bh][d][s]: bf16x8 at vt[d*512+k] IS the B-fragment; 64KB/bh, L2-hot;
// all 16 qt-blocks of a bh land on one XCD since gridX=128 = 0 mod 8).
// Softmax math identical to verified v1/edge_attn_k.
// ---------------------------------------------------------------------------
__global__ __launch_bounds__(256)
void edge_fused_k(const float* __restrict__ h0, const float* __restrict__ h1,
                  const int* __restrict__ grh, const bf16* __restrict__ vt,
                  bf16* __restrict__ ctx, int view)
{
  __shared__ short P[32 * 512];   // 32 KB
  const int tid = threadIdx.x;
  const int w = tid >> 6, ln = tid & 63;
  const int ln15 = ln & 15, quad = ln >> 4;
  const int bh = blockIdx.x, qt = blockIdx.y;   // qt in [0,16)
  const int bl = bh >> 4;

  // ---- phase 1: rows w*8 .. w*8+7, one full wave per row ----
  const int kb = ln * 8;
  {
    const float* hjp = h1 + (size_t)bh * 512 + kb;
    float4 hA = *(const float4*)hjp;
    float4 hB = *(const float4*)(hjp + 4);
    float hjv[8] = {hA.x, hA.y, hA.z, hA.w, hB.x, hB.y, hB.z, hB.w};
    const float* h0b = h0 + (size_t)bh * 512 + qt * 32 + w * 8;
    const int* grow = grh + ((size_t)bl * 512 + qt * 32 + w * 8) * 512 + kb;

    int4 ga = *(const int4*)grow;
    int4 gb = *(const int4*)(grow + 4);
    #pragma unroll 2
    for (int rr = 0; rr < 8; rr++) {
      // prefetch next row's mask (last iter re-reads own row: in-bounds, cheap)
      int rn = rr < 7 ? rr + 1 : rr;
      const int* gn = grow + (size_t)rn * 512;
      int4 gan = *(const int4*)gn;
      int4 gbn = *(const int4*)(gn + 4);
      int r = w * 8 + rr;              // local row in P, 0..31
      int qi = qt * 32 + r;            // global q index, 0..511
      float hi = h0b[rr];
      int g[8] = {ga.x, ga.y, ga.z, ga.w, gb.x, gb.y, gb.z, gb.w};
      float e[8];
      float m = -3.0e38f;
      #pragma unroll
      for (int j = 0; j < 8; j++) {
        float ej = hi + hjv[j];
        ej = ej >= 0.f ? ej : 0.01f * ej;
        int k = kb + j;
        bool adj;
        if (view == 0) adj = g[j] > 1;
        else if (view == 1) adj = g[j] == ((k == qi) ? 4 : 2);
        else if (view == 2) adj = g[j] == ((k == qi) ? 4 : 3);
        else adj = g[j] == 4;
        e[j] = adj ? ej : NEGV;
        m = fmaxf(m, e[j]);
      }
      #pragma unroll
      for (int off = 32; off; off >>= 1) m = fmaxf(m, __shfl_xor(m, off));
      float ssum = 0.f;
      #pragma unroll
      for (int j = 0; j < 8; j++) { e[j] = __expf(e[j] - m); ssum += e[j]; }
      #pragma unroll
      for (int off = 32; off; off >>= 1) ssum += __shfl_xor(ssum, off);
      float inv = 1.f / ssum;
      bf16x8 pv;
      #pragma unroll
      for (int j = 0; j < 8; j++) pv[j] = (short)f2us(e[j] * inv);
      // logical col-group ln (cols ln*8..+7), stored at group ln^(r&7)
      *(bf16x8*)&P[r * 512 + ((ln ^ (r & 7)) * 8)] = pv;
      ga = gan; gb = gbn;
    }
  }
  __syncthreads();

  // ---- phase 2: ctx[rows, d] = P @ V^T, V straight from global ----
  const bf16* vb = vt + (size_t)bh * 64 * 512;
  const int m0 = (w >> 1) * 16, d0 = (w & 1) * 32;
  f32x4 acc[2];
  acc[0] = (f32x4)(0.0f); acc[1] = (f32x4)(0.0f);

  const int ra = m0 + ln15;
  const int rsw = ra & 7;
  #pragma unroll 4
  for (int k0 = 0; k0 < 512; k0 += 32) {
    int gsel = (k0 >> 3) + quad;   // 16B-group index, 0..63
    bf16x8 a = *(bf16x8*)&P[ra * 512 + ((gsel ^ rsw) * 8)];
    #pragma unroll
    for (int nt = 0; nt < 2; nt++) {
      bf16x8 b = *(const bf16x8*)(vb + (size_t)(d0 + nt * 16 + ln15) * 512 + k0 + quad * 8);
      acc[nt] = mfma_bf16(a, b, acc[nt]);
    }
  }

  const int head = bh & 15;
  #pragma unroll
  for (int r = 0; r < 4; r++) {
    int s = qt * 32 + m0 + quad * 4 + r;
    #pragma unroll
    for (int nt = 0; nt < 2; nt++)
      ctx[((size_t)bl * 512 + s) * 1024 + head * 64 + d0 + nt * 16 + ln15] =
          __float2bfloat16(acc[nt][r]);
  }
}

// ---------------------------------------------------------------------------
__global__ __launch_bounds__(256)
void finish_k(const float* __restrict__ acc, const void* __restrict__ sub_b,
              void* __restrict__ dout, const int* __restrict__ dflag)
{
  const int isbf = *dflag;
  int i = blockIdx.x * 256 + threadIdx.x;
  float4 a = ((const float4*)acc)[i];
  int c = (i * 4) & 1023;
  float o0 = a.x + ldx(sub_b, c + 0, isbf);
  float o1 = a.y + ldx(sub_b, c + 1, isbf);
  float o2 = a.z + ldx(sub_b, c + 2, isbf);
  float o3 = a.w + ldx(sub_b, c + 3, isbf);
  if (isbf) {
    ushort4 u;
    u.x = f2us(o0); u.y = f2us(o1); u.z = f2us(o2); u.w = f2us(o3);
    ((ushort4*)dout)[i] = u;
  } else {
    ((float4*)dout)[i] = make_float4(o0, o1, o2, o3);
  }
}

// ---------------------------------------------------------------------------
extern "C" void kernel_launch(void* const* d_in, const int* in_sizes, int n_in,
                              void* d_out, int out_size, void* d_ws, size_t ws_size,
                              hipStream_t stream)
{
  const void* key   = d_in[0];
  const void* value = d_in[1];
  const void* query = d_in[2];
  const int*  grh   = (const int*)d_in[3];
  const void* Wq = d_in[5];
  const void* bq = d_in[6];
  const void* Wk = d_in[7];
  const void* bk = d_in[8];
  const void* Wv = d_in[9];
  const void* bv = d_in[10];
  const void* rel_emb = d_in[11];
  const void* att_w = d_in[12];
  const void* att_b = d_in[13];
  const void* gate_w = d_in[14];
  const void* gate_b = d_in[15];
  const void* sub_w = d_in[16];
  const void* sub_b = d_in[17];

  // chunking: fixed 19,595,280 fl + NB * 2,891,776 fl
  size_t ws_f = ws_size / 4;
  int NB = 1;
  for (int cand = 8; cand >= 1; cand >>= 1) {
    size_t need = 19595280ull + (size_t)cand * 2891776ull;
    if (need <= ws_f) { NB = cand; break; }
  }
  const int nch = 8 / NB;

  int* dflag = (int*)d_ws;
  float* base = (float*)d_ws;
  bf16* qbf = (bf16*)(base + 16);
  bf16* kbf = (bf16*)(base + 16 + 2097152);
  bf16* vtb = (bf16*)(base + 16 + 2 * 2097152);
  bf16* Wt  = (bf16*)(base + 16 + 3 * 2097152);
  float* G  = base + 16 + 3 * 2097152 + 6815744;
  float* h0 = G + 2162688;
  float* h1 = h0 + 65536;
  float* out_acc = h1 + 65536;
  bf16* ctx_c   = (bf16*)(out_acc + 4194304);
  bf16* gated_c = ctx_c + (size_t)NB * 524288;
  float* arel_c = (float*)(gated_c + (size_t)NB * 524288);
  bf16*  attn_c = (bf16*)(arel_c + (size_t)NB * 270336);

  const size_t WSL = 1048576;   // bf16 elems per weight slot

  detect_k<<<dim3(1), dim3(64), 0, stream>>>(Wq, dflag);

  // weights -> bf16 [n][k]: slots 0..2 QKV, 3..7 gate {0,5,1,2,3}, 8..12 sub
  wtrans_k<<<dim3(256), dim3(256), 0, stream>>>(Wq, 0, Wt + 0 * WSL, dflag);
  wtrans_k<<<dim3(256), dim3(256), 0, stream>>>(Wk, 0, Wt + 1 * WSL, dflag);
  wtrans_k<<<dim3(256), dim3(256), 0, stream>>>(Wv, 0, Wt + 2 * WSL, dflag);
  const int gate_srcs[5] = {0, 5, 1, 2, 3};
  for (int j = 0; j < 5; j++)
    wtrans_k<<<dim3(256), dim3(256), 0, stream>>>(gate_w, (size_t)gate_srcs[j] * WSL,
                                                  Wt + (size_t)(3 + j) * WSL, dflag);
  for (int c = 0; c < 5; c++)
    wtrans_k<<<dim3(256), dim3(256), 0, stream>>>(sub_w, (size_t)c * WSL,
                                                  Wt + (size_t)(8 + c) * WSL, dflag);

  // QKV projections (q scaled; v transposed to [bh][d][s])
  gemm_mfma<0, true><<<dim3(32, 8), dim3(256), 0, stream>>>(
      query, Wt + 0 * WSL, bq, qbf, nullptr, nullptr, dflag, 0, 0.125f, 0, 0);
  gemm_mfma<0, true><<<dim3(32, 8), dim3(256), 0, stream>>>(
      key, Wt + 1 * WSL, bk, kbf, nullptr, nullptr, dflag, 0, 1.0f, 0, 0);
  gemm_mfma<0, true><<<dim3(32, 8), dim3(256), 0, stream>>>(
      value, Wt + 2 * WSL, bv, vtb, nullptr, nullptr, dflag, 0, 1.0f, 0, 1);

  qrel_k<<<dim3(16384), dim3(256), 0, stream>>>(qbf, rel_emb, G, dflag);

  // main view
  for (int c = 0; c < nch; c++) {
    size_t ro = (size_t)c * NB * 8192;
    score_k<<<dim3(NB * 16, 8), dim3(256), 0, stream>>>(
        qbf + ro * 64, kbf + ro * 64, G + ro * 33, attn_c, arel_c,
        d_out, c * NB, dflag);
    ctx_mfma<1><<<dim3(NB * 16, 4), dim3(256), 0, stream>>>(
        attn_c, vtb + ro * 64, arel_c, rel_emb, ctx_c, dflag);
    gemm_mfma<1, false><<<dim3(NB * 4, 8), dim3(256), 0, stream>>>(
        ctx_c, Wt + 3 * WSL, gate_b, gated_c, nullptr, ctx_c, dflag, 0, 1.f, 0, 0);
    gemm_mfma<2, false><<<dim3(NB * 4, 8), dim3(256), 0, stream>>>(
        gated_c, Wt + 8 * WSL, nullptr, nullptr, out_acc + ro * 64, nullptr,
        dflag, 0, 1.f, 0, 0);
  }

  // edge views: fused softmax+PV (no attn HBM round-trip), 32 rows/block
  const int i0s[4] = {6, 0, 2, 4};
  const int i1s[4] = {7, 1, 3, 5};
  const int gis[4] = {5, 1, 2, 3};
  for (int v = 0; v < 4; v++) {
    hv_k<<<dim3(128), dim3(256), 0, stream>>>(vtb, att_w, att_b, i0s[v], i1s[v],
                                              h0, h1, dflag);
    for (int c = 0; c < nch; c++) {
      size_t ro = (size_t)c * NB * 8192;
      edge_fused_k<<<dim3(NB * 16, 16), dim3(256), 0, stream>>>(
          h0 + ro, h1 + ro, grh + (size_t)c * NB * 262144, vtb + ro * 64,
          ctx_c, v);
      gemm_mfma<1, false><<<dim3(NB * 4, 8), dim3(256), 0, stream>>>(
          ctx_c, Wt + (size_t)(4 + v) * WSL, gate_b, gated_c, nullptr, ctx_c,
          dflag, (size_t)gis[v] * 1024, 1.f, 0, 0);
      gemm_mfma<2, false><<<dim3(NB * 4, 8), dim3(256), 0, stream>>>(
          gated_c, Wt + (size_t)(9 + v) * WSL, nullptr, nullptr,
          out_acc + ro * 64, nullptr, dflag, 0, 1.f, 1, 0);
    }
  }

  finish_k<<<dim3(4096), dim3(256), 0, stream>>>(out_acc, sub_b, d_out, dflag);
}

// Round 3
// 958.553 us; speedup vs baseline: 1.2359x; 1.2089x over previous
//
#include <hip/hip_runtime.h>
#include <hip/hip_bf16.h>

typedef __hip_bfloat16 bf16;
typedef __attribute__((ext_vector_type(8))) short bf16x8;
typedef __attribute__((ext_vector_type(4))) float f32x4;

#define B_ 8
#define S_ 512
#define D_ 1024
#define H_ 16
#define NEGV -9.0e15f
#define WSL 1048576ull

__device__ __forceinline__ float bf2f(bf16 x) { return __bfloat162float(x); }
__device__ __forceinline__ float us2f(unsigned short u) {
  union { unsigned int i; float f; } c; c.i = ((unsigned int)u) << 16; return c.f;
}
__device__ __forceinline__ unsigned short f2us(float f) {
  bf16 h = __float2bfloat16(f);
  unsigned short u; __builtin_memcpy(&u, &h, 2); return u;
}
__device__ __forceinline__ float ldx(const void* p, size_t i, int isbf) {
  return isbf ? bf2f(((const bf16*)p)[i]) : ((const float*)p)[i];
}
struct F4 { float x, y, z, w; };
__device__ __forceinline__ F4 ld4(const void* p, size_t i, int isbf) {
  F4 r;
  if (isbf) {
    ushort4 u = *(const ushort4*)((const bf16*)p + i);
    r.x = us2f(u.x); r.y = us2f(u.y); r.z = us2f(u.z); r.w = us2f(u.w);
  } else {
    float4 d = *(const float4*)((const float*)p + i);
    r.x = d.x; r.y = d.y; r.z = d.z; r.w = d.w;
  }
  return r;
}
// 8 consecutive elements as bf16x8; converts if source is f32
__device__ __forceinline__ bf16x8 ld8bf(const void* p, size_t i, int isbf) {
  if (isbf) return *(const bf16x8*)((const bf16*)p + i);
  float4 a = *(const float4*)((const float*)p + i);
  float4 b = *(const float4*)((const float*)p + i + 4);
  bf16x8 r;
  r[0] = (short)f2us(a.x); r[1] = (short)f2us(a.y);
  r[2] = (short)f2us(a.z); r[3] = (short)f2us(a.w);
  r[4] = (short)f2us(b.x); r[5] = (short)f2us(b.y);
  r[6] = (short)f2us(b.z); r[7] = (short)f2us(b.w);
  return r;
}
__device__ __forceinline__ f32x4 mfma_bf16(bf16x8 a, bf16x8 b, f32x4 c) {
  return __builtin_amdgcn_mfma_f32_16x16x32_bf16(a, b, c, 0, 0, 0);
}

// Dtype detector (round-3 verified: picks f32 on this harness).
__global__ void detect_k(const void* __restrict__ w, int* __restrict__ flag)
{
  if (threadIdx.x == 0 && blockIdx.x == 0) {
    const unsigned short* u = (const unsigned short*)w;
    int sane = 0;
    for (int i = 0; i < 1024; i += 2) {
      float a = fabsf(us2f(u[i]));
      if (a == 0.f || (a > 9.5e-7f && a < 8.f)) sane++;
    }
    *flag = (sane > 256) ? 1 : 0;
  }
}

// ---------------------------------------------------------------------------
// ALL 13 weight transposes in one launch. slot = blockIdx.x>>8:
// 0..2 = Wq,Wk,Wv; 3..7 = gate_w srcs {0,5,1,2,3}; 8..12 = sub_w rows c.
// out[n][k] (bf16, 1024x1024) <- W[k][n] (per dflag dtype).
// ---------------------------------------------------------------------------
__global__ __launch_bounds__(256)
void wtrans_all_k(const void* __restrict__ Wq, const void* __restrict__ Wk,
                  const void* __restrict__ Wv, const void* __restrict__ gate_w,
                  const void* __restrict__ sub_w, bf16* __restrict__ Wt,
                  const int* __restrict__ dflag)
{
  const int isbf = *dflag;
  const int slot = blockIdx.x >> 8;
  const int blk = blockIdx.x & 255;
  const int gsrc[5] = {0, 5, 1, 2, 3};
  const void* W;
  size_t woff;
  if (slot < 3)      { W = slot == 0 ? Wq : (slot == 1 ? Wk : Wv); woff = 0; }
  else if (slot < 8) { W = gate_w; woff = (size_t)gsrc[slot - 3] * WSL; }
  else               { W = sub_w;  woff = (size_t)(slot - 8) * WSL; }
  bf16* out = Wt + (size_t)slot * WSL;

  __shared__ float t[64][68];
  const int tid = threadIdx.x;
  const int nt = blk & 15, kt = blk >> 4;
  {
    int r = tid >> 4, c4 = (tid & 15) * 4;
    #pragma unroll
    for (int i = 0; i < 4; i++) {
      int rr = r + i * 16;
      F4 v = ld4(W, woff + (size_t)(kt * 64 + rr) * 1024 + nt * 64 + c4, isbf);
      *(float4*)&t[rr][c4] = make_float4(v.x, v.y, v.z, v.w);
    }
  }
  __syncthreads();
  {
    int n = tid >> 4, k4 = (tid & 15) * 4;
    #pragma unroll
    for (int i = 0; i < 4; i++) {
      int nn = n + i * 16;
      ushort4 u;
      u.x = f2us(t[k4 + 0][nn]); u.y = f2us(t[k4 + 1][nn]);
      u.z = f2us(t[k4 + 2][nn]); u.w = f2us(t[k4 + 3][nn]);
      *(ushort4*)(out + (size_t)(nt * 64 + nn) * 1024 + kt * 64 + k4) = u;
    }
  }
}

// ---------------------------------------------------------------------------
// QKV projections, z-batched (z=0:q scaled, z=1:k, z=2:v transposed).
// 128x128 tile, BK=64, XOR-swizzled LDS (verified core).
// ---------------------------------------------------------------------------
__global__ __launch_bounds__(256)
void qkv_gemm_k(const void* __restrict__ Aq, const void* __restrict__ Ak,
                const void* __restrict__ Av, const bf16* __restrict__ Wt,
                const void* __restrict__ bqp, const void* __restrict__ bkp,
                const void* __restrict__ bvp, bf16* __restrict__ qbf,
                bf16* __restrict__ kbf, bf16* __restrict__ vtb,
                const int* __restrict__ dflag)
{
  const int isbf = *dflag;
  const int z = blockIdx.z;
  const void* A = z == 0 ? Aq : (z == 1 ? Ak : Av);
  const void* bias = z == 0 ? bqp : (z == 1 ? bkp : bvp);
  bf16* outB = z == 0 ? qbf : (z == 1 ? kbf : vtb);
  const bf16* Wz = Wt + (size_t)z * WSL;
  const float scale = z == 0 ? 0.125f : 1.0f;
  const int vtrans = (z == 2);

  __shared__ short As[128 * 64];
  __shared__ short Bs[128 * 64];
  const int tid = threadIdx.x;
  const int w = tid >> 6, ln = tid & 63;
  const int ln15 = ln & 15, quad = ln >> 4;
  const int wm = (w & 1) * 64, wn = (w >> 1) * 64;
  const int bm = blockIdx.x * 128, bn = blockIdx.y * 128;
  const int r0 = tid >> 3, g0 = tid & 7;
  f32x4 acc[4][4];
  #pragma unroll
  for (int mt = 0; mt < 4; mt++)
    #pragma unroll
    for (int nt = 0; nt < 4; nt++) acc[mt][nt] = (f32x4)(0.0f);

  for (int k0 = 0; k0 < 1024; k0 += 64) {
    #pragma unroll
    for (int i = 0; i < 4; i++) {
      int r = r0 + i * 32;
      int gsw = ((g0 ^ (r & 7)) * 8);
      bf16x8 av = ld8bf(A, (size_t)(bm + r) * 1024 + k0 + g0 * 8, isbf);
      *(bf16x8*)&As[r * 64 + gsw] = av;
      bf16x8 bv = *(const bf16x8*)(Wz + (size_t)(bn + r) * 1024 + k0 + g0 * 8);
      *(bf16x8*)&Bs[r * 64 + gsw] = bv;
    }
    __syncthreads();
    #pragma unroll
    for (int s = 0; s < 2; s++) {
      bf16x8 af[4], bfr[4];
      #pragma unroll
      for (int t = 0; t < 4; t++) {
        int ra = wm + t * 16 + ln15;
        af[t] = *(bf16x8*)&As[ra * 64 + (((s * 4 + quad) ^ (ra & 7)) * 8)];
        int rb = wn + t * 16 + ln15;
        bfr[t] = *(bf16x8*)&Bs[rb * 64 + (((s * 4 + quad) ^ (rb & 7)) * 8)];
      }
      #pragma unroll
      for (int mt = 0; mt < 4; mt++)
        #pragma unroll
        for (int nt = 0; nt < 4; nt++)
          acc[mt][nt] = mfma_bf16(af[mt], bfr[nt], acc[mt][nt]);
    }
    __syncthreads();
  }

  #pragma unroll
  for (int nt = 0; nt < 4; nt++) {
    int col = bn + wn + nt * 16 + ln15;
    float bv = ldx(bias, col, isbf);
    #pragma unroll
    for (int mt = 0; mt < 4; mt++) {
      #pragma unroll
      for (int r = 0; r < 4; r++) {
        int row = bm + wm + mt * 16 + quad * 4 + r;
        float v = (acc[mt][nt][r] + bv) * scale;
        int bb = row >> 9, s = row & 511;
        int h = col >> 6, d0 = col & 63;
        size_t o = vtrans ? (((size_t)(bb * 16 + h) * 64 + d0) * 512 + s)
                          : (((size_t)(bb * 16 + h) * 512 + s) * 64 + d0);
        outB[o] = __float2bfloat16(v);
      }
    }
  }
}

// ---------------------------------------------------------------------------
// Gate GEMMs, z-batched over 5 views (main + 4 edge).
// gated_z = sigmoid(ctx_z @ gate_w_z + gate_b_z) * ctx_z
// ---------------------------------------------------------------------------
__global__ __launch_bounds__(256)
void gate_gemm_k(const bf16* __restrict__ ctx5, const bf16* __restrict__ Wt,
                 const void* __restrict__ gate_b, bf16* __restrict__ gated5,
                 const int* __restrict__ dflag)
{
  const int isbf = *dflag;
  const int z = blockIdx.z;
  const int gsel[5] = {0, 5, 1, 2, 3};
  const bf16* A = ctx5 + (size_t)z * 4194304;
  bf16* outB = gated5 + (size_t)z * 4194304;
  const bf16* Wz = Wt + (size_t)(3 + z) * WSL;
  const size_t boff = (size_t)gsel[z] * 1024;

  __shared__ short As[128 * 64];
  __shared__ short Bs[128 * 64];
  const int tid = threadIdx.x;
  const int w = tid >> 6, ln = tid & 63;
  const int ln15 = ln & 15, quad = ln >> 4;
  const int wm = (w & 1) * 64, wn = (w >> 1) * 64;
  const int bm = blockIdx.x * 128, bn = blockIdx.y * 128;
  const int r0 = tid >> 3, g0 = tid & 7;
  f32x4 acc[4][4];
  #pragma unroll
  for (int mt = 0; mt < 4; mt++)
    #pragma unroll
    for (int nt = 0; nt < 4; nt++) acc[mt][nt] = (f32x4)(0.0f);

  for (int k0 = 0; k0 < 1024; k0 += 64) {
    #pragma unroll
    for (int i = 0; i < 4; i++) {
      int r = r0 + i * 32;
      int gsw = ((g0 ^ (r & 7)) * 8);
      bf16x8 av = *(const bf16x8*)(A + (size_t)(bm + r) * 1024 + k0 + g0 * 8);
      *(bf16x8*)&As[r * 64 + gsw] = av;
      bf16x8 bv = *(const bf16x8*)(Wz + (size_t)(bn + r) * 1024 + k0 + g0 * 8);
      *(bf16x8*)&Bs[r * 64 + gsw] = bv;
    }
    __syncthreads();
    #pragma unroll
    for (int s = 0; s < 2; s++) {
      bf16x8 af[4], bfr[4];
      #pragma unroll
      for (int t = 0; t < 4; t++) {
        int ra = wm + t * 16 + ln15;
        af[t] = *(bf16x8*)&As[ra * 64 + (((s * 4 + quad) ^ (ra & 7)) * 8)];
        int rb = wn + t * 16 + ln15;
        bfr[t] = *(bf16x8*)&Bs[rb * 64 + (((s * 4 + quad) ^ (rb & 7)) * 8)];
      }
      #pragma unroll
      for (int mt = 0; mt < 4; mt++)
        #pragma unroll
        for (int nt = 0; nt < 4; nt++)
          acc[mt][nt] = mfma_bf16(af[mt], bfr[nt], acc[mt][nt]);
    }
    __syncthreads();
  }

  #pragma unroll
  for (int nt = 0; nt < 4; nt++) {
    int col = bn + wn + nt * 16 + ln15;
    float bv = ldx(gate_b, boff + col, isbf);
    #pragma unroll
    for (int mt = 0; mt < 4; mt++) {
      #pragma unroll
      for (int r = 0; r < 4; r++) {
        int row = bm + wm + mt * 16 + quad * 4 + r;
        float v = acc[mt][nt][r] + bv;
        float x = bf2f(A[(size_t)row * 1024 + col]);
        outB[(size_t)row * 1024 + col] = __float2bfloat16(x / (1.f + __expf(-v)));
      }
    }
  }
}

// ---------------------------------------------------------------------------
// Final sub GEMM: out = [gated_0|...|gated_4](4096x5120) @ sub_w(5120x1024)
// + sub_b, written straight to d_out (dtype-aware). Replaces 5 GEMMs +
// the out_acc f32 RMW chain + finish_k.
// ---------------------------------------------------------------------------
__global__ __launch_bounds__(256)
void sub_gemm_k(const bf16* __restrict__ gated5, const bf16* __restrict__ Wt,
                const void* __restrict__ sub_b, void* __restrict__ dout,
                const int* __restrict__ dflag)
{
  const int isbf = *dflag;
  __shared__ short As[128 * 64];
  __shared__ short Bs[128 * 64];
  const int tid = threadIdx.x;
  const int w = tid >> 6, ln = tid & 63;
  const int ln15 = ln & 15, quad = ln >> 4;
  const int wm = (w & 1) * 64, wn = (w >> 1) * 64;
  const int bm = blockIdx.x * 128, bn = blockIdx.y * 128;
  const int r0 = tid >> 3, g0 = tid & 7;
  f32x4 acc[4][4];
  #pragma unroll
  for (int mt = 0; mt < 4; mt++)
    #pragma unroll
    for (int nt = 0; nt < 4; nt++) acc[mt][nt] = (f32x4)(0.0f);

  for (int k0 = 0; k0 < 5120; k0 += 64) {
    const int slot = k0 >> 10, kk = k0 & 1023;
    const bf16* Ab = gated5 + (size_t)slot * 4194304;
    const bf16* Wz = Wt + (size_t)(8 + slot) * WSL;
    #pragma unroll
    for (int i = 0; i < 4; i++) {
      int r = r0 + i * 32;
      int gsw = ((g0 ^ (r & 7)) * 8);
      bf16x8 av = *(const bf16x8*)(Ab + (size_t)(bm + r) * 1024 + kk + g0 * 8);
      *(bf16x8*)&As[r * 64 + gsw] = av;
      bf16x8 bv = *(const bf16x8*)(Wz + (size_t)(bn + r) * 1024 + kk + g0 * 8);
      *(bf16x8*)&Bs[r * 64 + gsw] = bv;
    }
    __syncthreads();
    #pragma unroll
    for (int s = 0; s < 2; s++) {
      bf16x8 af[4], bfr[4];
      #pragma unroll
      for (int t = 0; t < 4; t++) {
        int ra = wm + t * 16 + ln15;
        af[t] = *(bf16x8*)&As[ra * 64 + (((s * 4 + quad) ^ (ra & 7)) * 8)];
        int rb = wn + t * 16 + ln15;
        bfr[t] = *(bf16x8*)&Bs[rb * 64 + (((s * 4 + quad) ^ (rb & 7)) * 8)];
      }
      #pragma unroll
      for (int mt = 0; mt < 4; mt++)
        #pragma unroll
        for (int nt = 0; nt < 4; nt++)
          acc[mt][nt] = mfma_bf16(af[mt], bfr[nt], acc[mt][nt]);
    }
    __syncthreads();
  }

  #pragma unroll
  for (int nt = 0; nt < 4; nt++) {
    int col = bn + wn + nt * 16 + ln15;
    float bv = ldx(sub_b, col, isbf);
    #pragma unroll
    for (int mt = 0; mt < 4; mt++) {
      #pragma unroll
      for (int r = 0; r < 4; r++) {
        int row = bm + wm + mt * 16 + quad * 4 + r;
        float v = acc[mt][nt][r] + bv;
        size_t o = (size_t)row * 1024 + col;
        if (isbf) ((bf16*)dout)[o] = __float2bfloat16(v);
        else      ((float*)dout)[o] = v;
      }
    }
  }
}

// ---------------------------------------------------------------------------
// G[row][r] = q_row . rel_emb[r] (bf16 q). One wave per row.
// ---------------------------------------------------------------------------
__global__ __launch_bounds__(256)
void qrel_k(const bf16* __restrict__ qbf, const void* __restrict__ rel_emb,
            float* __restrict__ G, const int* __restrict__ dflag)
{
  const int isbf = *dflag;
  __shared__ float rel[33][65];
  __shared__ float qw[4][64];
  const int tid = threadIdx.x;
  for (int i = tid; i < 33 * 64; i += 256)
    rel[i >> 6][i & 63] = ldx(rel_emb, i, isbf);
  const int wv = tid >> 6, lane = tid & 63;
  const size_t row = (size_t)blockIdx.x * 4 + wv;
  qw[wv][lane] = bf2f(qbf[row * 64 + lane]);
  __syncthreads();
  if (lane < 33) {
    float s = 0.f;
    #pragma unroll
    for (int d = 0; d < 64; d++) s += qw[wv][d] * rel[lane][d];
    G[row * 33 + lane] = s;
  }
}

// ---------------------------------------------------------------------------
// Fully fused main view: QK^T + rel bias + softmax + top_attn + PV MFMA +
// arel@rel epilogue -> ctx (slot 0). P lives only in LDS; attn/arel buffers
// eliminated. QK/softmax math identical to verified score_k; PV fragment
// pattern identical to verified edge_fused/ctx_mfma (V direct from global,
// vt [bh][d][s] is fragment-ready).
// ---------------------------------------------------------------------------
__global__ __launch_bounds__(256)
void score_fused_k(const bf16* __restrict__ qbf, const bf16* __restrict__ kbf,
                   const float* __restrict__ G, const bf16* __restrict__ vt,
                   const void* __restrict__ rel_emb, bf16* __restrict__ ctx,
                   void* __restrict__ dout, const int* __restrict__ dflag)
{
  __shared__ short smem[64 * 512];
  short* qs = smem;
  short* ks = smem + 64 * 72;
  float* gl = (float*)(smem + 2 * 64 * 72);
  const int tid = threadIdx.x;
  const int w = tid >> 6, ln = tid & 63;
  const int ln15 = ln & 15, quad = ln >> 4;
  const int bh = blockIdx.x, qt = blockIdx.y;
  const size_t qrow0 = (size_t)bh * 512 + qt * 64;
  const int isbf = *dflag;

  #pragma unroll
  for (int i = 0; i < 4; i++) {
    int idx = tid + i * 256;
    int r = idx >> 4, c4 = (idx & 15) * 4;
    ushort4 u = *(const ushort4*)(qbf + (qrow0 + r) * 64 + c4);
    *(ushort4*)&qs[r * 72 + c4] = u;
  }
  for (int i = tid; i < 64 * 33; i += 256) {
    int r = i / 33, c = i - r * 33;
    gl[i] = G[(qrow0 + r) * 33 + c];
  }

  f32x4 acc[32];
  #pragma unroll
  for (int t = 0; t < 32; t++) acc[t] = (f32x4)(0.0f);

  const size_t kbase = (size_t)bh * 512 * 64;
  for (int kc = 0; kc < 8; kc++) {
    __syncthreads();
    #pragma unroll
    for (int i = 0; i < 4; i++) {
      int idx = tid + i * 256;
      int r = idx >> 4, c4 = (idx & 15) * 4;
      ushort4 u = *(const ushort4*)(kbf + kbase + (size_t)(kc * 64 + r) * 64 + c4);
      *(ushort4*)&ks[r * 72 + c4] = u;
    }
    __syncthreads();
    #pragma unroll
    for (int ds = 0; ds < 64; ds += 32) {
      bf16x8 a = *(bf16x8*)&qs[(w * 16 + ln15) * 72 + ds + quad * 8];
      #pragma unroll
      for (int nt = 0; nt < 4; nt++) {
        bf16x8 b = *(bf16x8*)&ks[(nt * 16 + ln15) * 72 + ds + quad * 8];
        acc[kc * 4 + nt] = mfma_bf16(a, b, acc[kc * 4 + nt]);
      }
    }
  }

  const int qg = qt * 64 + w * 16 + quad * 4;
  const int rowl0 = w * 16 + quad * 4;
  float mx[4], ssum[4], sle[4], sge[4];
  #pragma unroll
  for (int r = 0; r < 4; r++) mx[r] = -3.0e38f;
  for (int t = 0; t < 32; t++) {
    int k = t * 16 + ln15;
    #pragma unroll
    for (int r = 0; r < 4; r++) {
      int delta = k - (qg + r);
      int bkt = delta < -16 ? 0 : (delta > 16 ? 32 : delta + 16);
      float s = acc[t][r] + gl[(rowl0 + r) * 33 + bkt];
      acc[t][r] = s;
      mx[r] = fmaxf(mx[r], s);
    }
  }
  #pragma unroll
  for (int r = 0; r < 4; r++) {
    float m = mx[r];
    #pragma unroll
    for (int off = 1; off < 16; off <<= 1) m = fmaxf(m, __shfl_xor(m, off));
    mx[r] = m;
    ssum[r] = 0.f; sle[r] = 0.f; sge[r] = 0.f;
  }
  for (int t = 0; t < 32; t++) {
    int k = t * 16 + ln15;
    #pragma unroll
    for (int r = 0; r < 4; r++) {
      float p = __expf(acc[t][r] - mx[r]);
      acc[t][r] = p;
      ssum[r] += p;
      int delta = k - (qg + r);
      if (delta <= -16) sle[r] += p;
      if (delta >= 16) sge[r] += p;
    }
  }
  #pragma unroll
  for (int r = 0; r < 4; r++) {
    #pragma unroll
    for (int off = 1; off < 16; off <<= 1) {
      ssum[r] += __shfl_xor(ssum[r], off);
      sle[r] += __shfl_xor(sle[r], off);
      sge[r] += __shfl_xor(sge[r], off);
    }
  }
  float inv[4];
  #pragma unroll
  for (int r = 0; r < 4; r++) inv[r] = 1.f / ssum[r];
  __syncthreads();

  // P (normalized, bf16) into LDS: P[row][k] at smem[row*512 + (k ^ (((row>>2)&3)<<4))]
  for (int t = 0; t < 32; t++) {
    int ksw = (t * 16 + ln15) ^ (quad << 4);
    #pragma unroll
    for (int r = 0; r < 4; r++)
      smem[(rowl0 + r) * 512 + ksw] = (short)f2us(acc[t][r] * inv[r]);
  }
  __syncthreads();

  // top_attn for head 0 (d_out offset 4194304)
  if ((bh & 15) == 0) {
    const int bg = bh >> 4;
    for (int i = tid; i < 64 * 128; i += 256) {
      int r = i >> 7, c4 = (i & 127) * 4;
      int ksw = c4 ^ (((r >> 2) & 3) << 4);
      ushort4 u = *(ushort4*)&smem[r * 512 + ksw];
      size_t o = (size_t)4194304 + (size_t)bg * 262144 + (size_t)(qt * 64 + r) * 512 + c4;
      if (isbf) {
        *(ushort4*)((bf16*)dout + o) = u;
      } else {
        float4 f = make_float4(us2f(u.x), us2f(u.y), us2f(u.z), us2f(u.w));
        *(float4*)((float*)dout + o) = f;
      }
    }
  }

  // ---- PV: ctx_rows = P @ V^T, V fragments straight from global ----
  const bf16* vb = vt + (size_t)bh * 64 * 512;
  f32x4 pacc[4];
  #pragma unroll
  for (int nt = 0; nt < 4; nt++) pacc[nt] = (f32x4)(0.0f);
  const int ra = w * 16 + ln15;
  const int rsw2 = ((ra >> 2) & 3) << 1;   // group-level XOR of the P swizzle
  #pragma unroll 4
  for (int kk = 0; kk < 16; kk++) {
    int g = kk * 4 + quad;
    bf16x8 a = *(bf16x8*)&smem[ra * 512 + ((g ^ rsw2) * 8)];
    int k0 = kk * 32;
    #pragma unroll
    for (int nt = 0; nt < 4; nt++) {
      bf16x8 b = *(const bf16x8*)(vb + (size_t)(nt * 16 + ln15) * 512 + k0 + quad * 8);
      pacc[nt] = mfma_bf16(a, b, pacc[nt]);
    }
  }

  // ---- arel @ rel epilogue: bkt 0 = sle, 32 = sge, middle = P diagonal band
  #pragma unroll 1
  for (int rr = 0; rr < 33; rr++) {
    float av[4];
    #pragma unroll
    for (int r = 0; r < 4; r++) {
      if (rr == 0)       av[r] = sle[r] * inv[r];
      else if (rr == 32) av[r] = sge[r] * inv[r];
      else {
        int rowl = rowl0 + r;
        int k = qt * 64 + rowl + rr - 16;
        av[r] = 0.f;
        if (k >= 0 && k < 512) {
          int ksw = k ^ (quad << 4);
          av[r] = us2f((unsigned short)smem[rowl * 512 + ksw]);
        }
      }
    }
    #pragma unroll
    for (int nt = 0; nt < 4; nt++) {
      float relv = ldx(rel_emb, rr * 64 + nt * 16 + ln15, isbf);
      #pragma unroll
      for (int r = 0; r < 4; r++) pacc[nt][r] += av[r] * relv;
    }
  }

  // ---- ctx write (slot 0 layout [bl*512+s][1024]) ----
  const int bl = bh >> 4, head = bh & 15;
  #pragma unroll
  for (int r = 0; r < 4; r++) {
    int s = qt * 64 + rowl0 + r;
    #pragma unroll
    for (int nt = 0; nt < 4; nt++)
      ctx[((size_t)bl * 512 + s) * 1024 + head * 64 + nt * 16 + ln15] =
          __float2bfloat16(pacc[nt][r]);
  }
}

// ---------------------------------------------------------------------------
// Edge h-projections, z-batched over 4 views (blockIdx.y).
// ---------------------------------------------------------------------------
__global__ __launch_bounds__(256)
void hv_k(const bf16* __restrict__ vt, const void* __restrict__ att_w,
          const void* __restrict__ att_b, float* __restrict__ h0,
          float* __restrict__ h1, const int* __restrict__ dflag)
{
  const int i0s[4] = {6, 0, 2, 4};
  const int i1s[4] = {7, 1, 3, 5};
  const int z = blockIdx.y;
  const int i0 = i0s[z], i1 = i1s[z];
  __shared__ float w0[64], w1[64];
  const int tid = threadIdx.x;
  const int bh = blockIdx.x;
  const int isbf = *dflag;
  if (tid < 64) {
    w0[tid] = ldx(att_w, i0 * 64 + tid, isbf);
    w1[tid] = ldx(att_w, i1 * 64 + tid, isbf);
  }
  __syncthreads();
  const bf16* vb = vt + (size_t)bh * 64 * 512 + tid * 2;
  float a00 = 0, a01 = 0, a10 = 0, a11 = 0;
  for (int d = 0; d < 64; d++) {
    ushort2 u = *(const ushort2*)(vb + (size_t)d * 512);
    float f0 = us2f(u.x), f1 = us2f(u.y);
    a00 += f0 * w0[d]; a10 += f1 * w0[d];
    a01 += f0 * w1[d]; a11 += f1 * w1[d];
  }
  float b0 = ldx(att_b, i0, isbf), b1 = ldx(att_b, i1, isbf);
  float* p0 = h0 + (size_t)z * 65536 + (size_t)bh * 512 + tid * 2;
  float* p1 = h1 + (size_t)z * 65536 + (size_t)bh * 512 + tid * 2;
  p0[0] = a00 + b0; p0[1] = a10 + b0;
  p1[0] = a01 + b1; p1[1] = a11 + b1;
}

// ---------------------------------------------------------------------------
// Fused edge view, z-batched over the 4 views (blockIdx.z). Same verified
// structure as round-2: 32 q-rows/block, 32KB LDS P, softmax per wave-row,
// PV with V fragments from global. Writes ctx5 slot (1+view).
// ---------------------------------------------------------------------------
__global__ __launch_bounds__(256)
void edge_fused_k(const float* __restrict__ h0, const float* __restrict__ h1,
                  const int* __restrict__ grh, const bf16* __restrict__ vt,
                  bf16* __restrict__ ctx5)
{
  __shared__ short P[32 * 512];   // 32 KB
  const int tid = threadIdx.x;
  const int w = tid >> 6, ln = tid & 63;
  const int ln15 = ln & 15, quad = ln >> 4;
  const int bh = blockIdx.x, qt = blockIdx.y, view = blockIdx.z;
  const int bl = bh >> 4;
  bf16* ctx = ctx5 + (size_t)(1 + view) * 4194304;

  // ---- phase 1: rows w*8 .. w*8+7, one full wave per row ----
  const int kb = ln * 8;
  {
    const float* hjp = h1 + (size_t)view * 65536 + (size_t)bh * 512 + kb;
    float4 hA = *(const float4*)hjp;
    float4 hB = *(const float4*)(hjp + 4);
    float hjv[8] = {hA.x, hA.y, hA.z, hA.w, hB.x, hB.y, hB.z, hB.w};
    const float* h0b = h0 + (size_t)view * 65536 + (size_t)bh * 512 + qt * 32 + w * 8;
    const int* grow = grh + ((size_t)bl * 512 + qt * 32 + w * 8) * 512 + kb;

    int4 ga = *(const int4*)grow;
    int4 gb = *(const int4*)(grow + 4);
    #pragma unroll 2
    for (int rr = 0; rr < 8; rr++) {
      int rn = rr < 7 ? rr + 1 : rr;
      const int* gn = grow + (size_t)rn * 512;
      int4 gan = *(const int4*)gn;
      int4 gbn = *(const int4*)(gn + 4);
      int r = w * 8 + rr;              // local row in P, 0..31
      int qi = qt * 32 + r;            // global q index, 0..511
      float hi = h0b[rr];
      int g[8] = {ga.x, ga.y, ga.z, ga.w, gb.x, gb.y, gb.z, gb.w};
      float e[8];
      float m = -3.0e38f;
      #pragma unroll
      for (int j = 0; j < 8; j++) {
        float ej = hi + hjv[j];
        ej = ej >= 0.f ? ej : 0.01f * ej;
        int k = kb + j;
        bool adj;
        if (view == 0) adj = g[j] > 1;
        else if (view == 1) adj = g[j] == ((k == qi) ? 4 : 2);
        else if (view == 2) adj = g[j] == ((k == qi) ? 4 : 3);
        else adj = g[j] == 4;
        e[j] = adj ? ej : NEGV;
        m = fmaxf(m, e[j]);
      }
      #pragma unroll
      for (int off = 32; off; off >>= 1) m = fmaxf(m, __shfl_xor(m, off));
      float ssum = 0.f;
      #pragma unroll
      for (int j = 0; j < 8; j++) { e[j] = __expf(e[j] - m); ssum += e[j]; }
      #pragma unroll
      for (int off = 32; off; off >>= 1) ssum += __shfl_xor(ssum, off);
      float inv = 1.f / ssum;
      bf16x8 pv;
      #pragma unroll
      for (int j = 0; j < 8; j++) pv[j] = (short)f2us(e[j] * inv);
      *(bf16x8*)&P[r * 512 + ((ln ^ (r & 7)) * 8)] = pv;
      ga = gan; gb = gbn;
    }
  }
  __syncthreads();

  // ---- phase 2: ctx[rows, d] = P @ V^T, V straight from global ----
  const bf16* vb = vt + (size_t)bh * 64 * 512;
  const int m0 = (w >> 1) * 16, d0 = (w & 1) * 32;
  f32x4 acc[2];
  acc[0] = (f32x4)(0.0f); acc[1] = (f32x4)(0.0f);

  const int ra = m0 + ln15;
  const int rsw = ra & 7;
  #pragma unroll 4
  for (int k0 = 0; k0 < 512; k0 += 32) {
    int gsel = (k0 >> 3) + quad;
    bf16x8 a = *(bf16x8*)&P[ra * 512 + ((gsel ^ rsw) * 8)];
    #pragma unroll
    for (int nt = 0; nt < 2; nt++) {
      bf16x8 b = *(const bf16x8*)(vb + (size_t)(d0 + nt * 16 + ln15) * 512 + k0 + quad * 8);
      acc[nt] = mfma_bf16(a, b, acc[nt]);
    }
  }

  const int head = bh & 15;
  #pragma unroll
  for (int r = 0; r < 4; r++) {
    int s = qt * 32 + m0 + quad * 4 + r;
    #pragma unroll
    for (int nt = 0; nt < 2; nt++)
      ctx[((size_t)bl * 512 + s) * 1024 + head * 64 + d0 + nt * 16 + ln15] =
          __float2bfloat16(acc[nt][r]);
  }
}

// ---------------------------------------------------------------------------
extern "C" void kernel_launch(void* const* d_in, const int* in_sizes, int n_in,
                              void* d_out, int out_size, void* d_ws, size_t ws_size,
                              hipStream_t stream)
{
  const void* key   = d_in[0];
  const void* value = d_in[1];
  const void* query = d_in[2];
  const int*  grh   = (const int*)d_in[3];
  const void* Wq = d_in[5];
  const void* bq = d_in[6];
  const void* Wk = d_in[7];
  const void* bk = d_in[8];
  const void* Wv = d_in[9];
  const void* bv = d_in[10];
  const void* rel_emb = d_in[11];
  const void* att_w = d_in[12];
  const void* att_b = d_in[13];
  const void* gate_w = d_in[14];
  const void* gate_b = d_in[15];
  const void* sub_w = d_in[16];
  const void* sub_b = d_in[17];

  // workspace layout (floats) — total 36,765,712 fl = 147 MB
  // (rounds 0-2 ran NB=8 chunking = 171 MB, so this fits)
  int* dflag = (int*)d_ws;
  float* base = (float*)d_ws;
  bf16* qbf = (bf16*)(base + 16);
  bf16* kbf = (bf16*)(base + 16 + 2097152);
  bf16* vtb = (bf16*)(base + 16 + 2 * 2097152);
  bf16* Wt  = (bf16*)(base + 16 + 3 * 2097152);
  float* G  = base + 16 + 3 * 2097152 + 6815744;
  float* h0 = G + 2162688;
  float* h1 = h0 + 262144;
  bf16* ctx5   = (bf16*)(h1 + 262144);
  bf16* gated5 = ctx5 + 5ull * 4194304;

  detect_k<<<dim3(1), dim3(64), 0, stream>>>(Wq, dflag);

  // all 13 weight transposes in one launch
  wtrans_all_k<<<dim3(13 * 256), dim3(256), 0, stream>>>(
      Wq, Wk, Wv, gate_w, sub_w, Wt, dflag);

  // QKV projections batched (z: 0=q scaled, 1=k, 2=v transposed)
  qkv_gemm_k<<<dim3(32, 8, 3), dim3(256), 0, stream>>>(
      query, key, value, Wt, bq, bk, bv, qbf, kbf, vtb, dflag);

  qrel_k<<<dim3(16384), dim3(256), 0, stream>>>(qbf, rel_emb, G, dflag);

  // main view fully fused -> ctx5 slot 0 (+ top_attn to d_out)
  score_fused_k<<<dim3(128, 8), dim3(256), 0, stream>>>(
      qbf, kbf, G, vtb, rel_emb, ctx5, d_out, dflag);

  // edge views: h projections (4 views batched), then fused softmax+PV
  hv_k<<<dim3(128, 4), dim3(256), 0, stream>>>(vtb, att_w, att_b, h0, h1, dflag);
  edge_fused_k<<<dim3(128, 16, 4), dim3(256), 0, stream>>>(
      h0, h1, grh, vtb, ctx5);

  // 5 gate GEMMs batched, then one K=5120 sub GEMM straight to d_out
  gate_gemm_k<<<dim3(32, 8, 5), dim3(256), 0, stream>>>(
      ctx5, Wt, gate_b, gated5, dflag);
  sub_gemm_k<<<dim3(32, 8), dim3(256), 0, stream>>>(
      gated5, Wt, sub_b, d_out, dflag);
}